// Round 4
// baseline (290.730 us; speedup 1.0000x reference)
//
#include <hip/hip_runtime.h>

// dims: S=128, E=256 -> 32768 pairs; H=20, D=64, A=64, NH=8
constexpr float TEMP = 2.5f;    // H / sqrt(A) = 20/8
constexpr float NEGV = -1e9f;

// ---- workspace layout (floats) ----
constexpr int M_OFF = 0;        // M[8][64][64]  (pre-scaled by TEMP)
constexpr int K_OFF = 32768;    // k[8][64]
constexpr int P_OFF = 33280;    // p[8][64]
constexpr int Q_OFF = 33792;    // q[8]

// ---- main-kernel LDS layout (floats) ----
constexpr int HT_OFF  = 0;      // ht[8][64]            (512)
constexpr int V_OFF   = 512;    // V/wv [8 pairs][520]  (4160)
constexpr int ATT_OFF = 4672;   // attn[8][20][12]      (1920)  16B-aligned rows
constexpr int Y_OFF   = 6592;   // y[8 pairs][8][66]    (4224)
constexpr int C_OFF   = 10816;  // c[8 pairs][8 heads]  (64)
constexpr int LEN_OFF = 10880;  // len[8]               (8)
constexpr int LDS_FL  = 10888;  // 43,552 B -> 3 blocks/CU (24 waves/CU)

// ============================================================
// prep: M[n][dp][d] = sum_a Wt[n][dp][a]*Ws[n][d][a];  k = Ws·bt;
//       p = Wt·bs;  q = bt·bs.  All scaled by TEMP.  (unchanged, verified)
// ============================================================
__global__ __launch_bounds__(256) void prep_kernel(
    const float* __restrict__ Wt, const float* __restrict__ bt,
    const float* __restrict__ Ws, const float* __restrict__ bs,
    float* __restrict__ ws) {
  __shared__ float WsL[64 * 65];
  __shared__ float WtL[16 * 65];
  const int t  = threadIdx.x;
  const int n  = blockIdx.x >> 2;
  const int q  = blockIdx.x & 3;
  const int dp0 = q * 16;
  const float* Wtn = Wt + n * 4096;
  const float* Wsn = Ws + n * 4096;
#pragma unroll
  for (int i = 0; i < 16; ++i) {
    const int idx = i * 256 + t;
    WsL[(idx >> 6) * 65 + (idx & 63)] = Wsn[idx];
  }
#pragma unroll
  for (int i = 0; i < 4; ++i) {
    const int idx = i * 256 + t;
    WtL[(idx >> 6) * 65 + (idx & 63)] = Wtn[dp0 * 64 + idx];
  }
  __syncthreads();
#pragma unroll
  for (int i = 0; i < 4; ++i) {
    const int idx = i * 256 + t;
    const int dpl = idx >> 6, d = idx & 63;
    const float* wtr = &WtL[dpl * 65];
    const float* wsr = &WsL[d * 65];
    float acc = 0.f;
#pragma unroll 8
    for (int a = 0; a < 64; ++a) acc += wtr[a] * wsr[a];
    ws[M_OFF + n * 4096 + (dp0 + dpl) * 64 + d] = acc * TEMP;
  }
  if (q == 0 && t < 64) {
    float acc = 0.f;
#pragma unroll 8
    for (int a = 0; a < 64; ++a) acc += WsL[t * 65 + a] * bt[n * 64 + a];
    ws[K_OFF + n * 64 + t] = acc * TEMP;
  }
  if (t >= 64 && t < 80) {
    const int r = t - 64;
    float acc = 0.f;
#pragma unroll 8
    for (int a = 0; a < 64; ++a) acc += WtL[r * 65 + a] * bs[n * 64 + a];
    ws[P_OFF + n * 64 + dp0 + r] = acc * TEMP;
  }
  if (q == 0 && t == 128) {
    float acc = 0.f;
    for (int a = 0; a < 64; ++a) acc += bt[n * 64 + a] * bs[n * 64 + a];
    ws[Q_OFF + n] = acc * TEMP;
  }
}

// ============================================================
// main: 8 pairs/block, 512 threads (8 waves), grid 4096.
// ht in LDS; M/Wf software-pipelined 8-deep; hs from L2/L3.
// ============================================================
__global__ __launch_bounds__(512, 6) void attn_kernel(
    const float* __restrict__ ht_g, const float* __restrict__ hs_g,
    const int* __restrict__ len_g, const float* __restrict__ Wf,
    const float* __restrict__ bf, const float* __restrict__ wsp,
    float* __restrict__ out) {
  __shared__ float lds[LDS_FL];
  const int t    = threadIdx.x;
  const int lane = t & 63;
  const int w    = t >> 6;            // wave id 0..7
  const int pair0 = blockIdx.x * 8;

  // ---------- stage ht (coalesced, 1 float/thread) + len ----------
  lds[HT_OFF + t] = ht_g[(size_t)pair0 * 64 + t];
  if (t < 8) lds[LEN_OFF + t] = (float)len_g[pair0 + t];
  __syncthreads();   // barrier A: ht visible

  // ---------- V phase: wave w = head n, lane = d ----------
  // V[p][n][d] = k[n][d] + sum_dp ht[p][dp] * M[n][dp][d]
  {
    const int n = w, d = lane;
    float acc[8];
    const float kv = wsp[K_OFF + n * 64 + d];
#pragma unroll
    for (int p = 0; p < 8; ++p) acc[p] = kv;
    const float* Mn = &wsp[M_OFF + n * 4096];
    float m[16];                       // 2 chunks of 8, static-indexed
#pragma unroll
    for (int j = 0; j < 8; ++j) m[j] = Mn[j * 64 + d];
#pragma unroll
    for (int c = 0; c < 8; ++c) {
      const int cur = (c & 1) * 8;
      const int nxt = ((c + 1) & 1) * 8;
      if (c < 7) {
#pragma unroll
        for (int j = 0; j < 8; ++j) m[nxt + j] = Mn[((c + 1) * 8 + j) * 64 + d];
      }
#pragma unroll
      for (int p = 0; p < 8; ++p) {
        const float4 h0 = *(const float4*)&lds[HT_OFF + p * 64 + c * 8];
        const float4 h1 = *(const float4*)&lds[HT_OFF + p * 64 + c * 8 + 4];
        acc[p] += h0.x * m[cur + 0] + h0.y * m[cur + 1]
                + h0.z * m[cur + 2] + h0.w * m[cur + 3]
                + h1.x * m[cur + 4] + h1.y * m[cur + 5]
                + h1.z * m[cur + 6] + h1.w * m[cur + 7];
      }
    }
    float* vp = &lds[V_OFF + n * 64 + d];
#pragma unroll
    for (int p = 0; p < 8; ++p) vp[p * 520] = acc[p];
  }

  // ---------- c[p][n] = q[n] + ht·p[n]  (8 lanes of each wave) ----------
  {
    const int n = w;
    if (lane < 8) {
      const float* htp = &lds[HT_OFF + lane * 64];
      float cacc = wsp[Q_OFF + n];
#pragma unroll 8
      for (int dp = 0; dp < 64; ++dp)
        cacc = fmaf(htp[dp], wsp[P_OFF + n * 64 + dp], cacc);
      lds[C_OFF + lane * 8 + n] = cacc;
    }
  }
  __syncthreads();   // barrier 1: V, c visible

  // ---------- P2: scores + softmax. wave = pair, halves = 4 heads each ----
  {
    const int p  = w;
    const int m_ = lane & 31;
    const int nn = lane >> 5;
    const int mm = (m_ < 20) ? m_ : 19;
    const bool act = (m_ < 20);
    const float4* hs4 = (const float4*)(hs_g + (size_t)(pair0 + p) * 1280 + mm * 64);
    const float* vb   = &lds[V_OFF + p * 520 + nn * 256];
    float s[4];
#pragma unroll
    for (int it = 0; it < 4; ++it) s[it] = lds[C_OFF + p * 8 + nn * 4 + it];
#pragma unroll
    for (int half = 0; half < 2; ++half) {
      float4 hb[8];
#pragma unroll
      for (int j = 0; j < 8; ++j) hb[j] = hs4[half * 8 + j];   // 8-deep MLP
#pragma unroll
      for (int j = 0; j < 8; ++j) {
#pragma unroll
        for (int it = 0; it < 4; ++it) {
          const float4 v4 = *(const float4*)&vb[it * 64 + (half * 8 + j) * 4];
          s[it] += hb[j].x * v4.x + hb[j].y * v4.y
                 + hb[j].z * v4.z + hb[j].w * v4.w;
        }
      }
    }
    const int lenp = (int)lds[LEN_OFF + p];
    float at[4];
#pragma unroll
    for (int it = 0; it < 4; ++it) {
      float sv = (act && m_ < lenp) ? s[it] : NEGV;
      float mx = sv;
#pragma unroll
      for (int o = 16; o; o >>= 1) mx = fmaxf(mx, __shfl_xor(mx, o, 32));
      const float e = act ? __expf(sv - mx) : 0.f;
      float sm = e;
#pragma unroll
      for (int o = 16; o; o >>= 1) sm += __shfl_xor(sm, o, 32);
      at[it] = e / sm;
    }
    if (act)
      *(float4*)&lds[ATT_OFF + p * 240 + m_ * 12 + nn * 4] =
          make_float4(at[0], at[1], at[2], at[3]);
  }
  // no barrier: P3 touches only this wave's pair

  // ---------- P3: wv[p][n][d] = sum_m attn[p][m][n]*hs[p][m][d] ----------
  {
    const int p = w, d = lane;
    const float* hsp = hs_g + (size_t)(pair0 + p) * 1280;
    float hr[20];
#pragma unroll
    for (int m_ = 0; m_ < 20; ++m_) hr[m_] = hsp[m_ * 64 + d];  // 20-deep MLP
    float wv[8] = {0.f, 0.f, 0.f, 0.f, 0.f, 0.f, 0.f, 0.f};
    const float* atp = &lds[ATT_OFF + p * 240];
#pragma unroll
    for (int m_ = 0; m_ < 20; ++m_) {
      const float4 a0 = *(const float4*)&atp[m_ * 12];
      const float4 a1 = *(const float4*)&atp[m_ * 12 + 4];
      wv[0] += a0.x * hr[m_]; wv[1] += a0.y * hr[m_];
      wv[2] += a0.z * hr[m_]; wv[3] += a0.w * hr[m_];
      wv[4] += a1.x * hr[m_]; wv[5] += a1.y * hr[m_];
      wv[6] += a1.z * hr[m_]; wv[7] += a1.w * hr[m_];
    }
    float* vd = &lds[V_OFF + p * 520 + d];   // overwrite V (dead after P2)
#pragma unroll
    for (int n = 0; n < 8; ++n) vd[n * 64] = wv[n];
  }
  __syncthreads();   // barrier 2: all pairs' wv visible

  // ---------- P4a: y[p][n][d] = sum_dd wv[p][n*64+dd]*Wf[n*64+dd][d] ------
  {
    const int n = w, d = lane;
    float acc[8] = {0.f, 0.f, 0.f, 0.f, 0.f, 0.f, 0.f, 0.f};
    const float* wfb = &Wf[n * 4096 + d];
    float wreg[16];                    // 2 chunks of 8, static-indexed
#pragma unroll
    for (int j = 0; j < 8; ++j) wreg[j] = wfb[j * 64];
#pragma unroll
    for (int c = 0; c < 8; ++c) {
      const int cur = (c & 1) * 8;
      const int nxt = ((c + 1) & 1) * 8;
      if (c < 7) {
#pragma unroll
        for (int j = 0; j < 8; ++j) wreg[nxt + j] = wfb[((c + 1) * 8 + j) * 64];
      }
#pragma unroll
      for (int p = 0; p < 8; ++p) {
        const float4 w0 = *(const float4*)&lds[V_OFF + p * 520 + n * 64 + c * 8];
        const float4 w1 = *(const float4*)&lds[V_OFF + p * 520 + n * 64 + c * 8 + 4];
        acc[p] += w0.x * wreg[cur + 0] + w0.y * wreg[cur + 1]
                + w0.z * wreg[cur + 2] + w0.w * wreg[cur + 3]
                + w1.x * wreg[cur + 4] + w1.y * wreg[cur + 5]
                + w1.z * wreg[cur + 6] + w1.w * wreg[cur + 7];
      }
    }
#pragma unroll
    for (int p = 0; p < 8; ++p)
      lds[Y_OFF + p * 528 + n * 66 + d] = acc[p];
  }
  __syncthreads();   // barrier 3

  // ---------- P4b: out[p][d] = bf[d] + sum_n y[p][n][d] ----------
  {
    const int p = t >> 6, d = t & 63;
    float o = bf[d];
#pragma unroll
    for (int n = 0; n < 8; ++n) o += lds[Y_OFF + p * 528 + n * 66 + d];
    out[(size_t)pair0 * 64 + t] = o;
  }
}

extern "C" void kernel_launch(void* const* d_in, const int* in_sizes, int n_in,
                              void* d_out, int out_size, void* d_ws, size_t ws_size,
                              hipStream_t stream) {
  const float* ht  = (const float*)d_in[0];
  const float* hs  = (const float*)d_in[1];
  const int*   len = (const int*)d_in[2];
  const float* Wt  = (const float*)d_in[3];
  const float* bt  = (const float*)d_in[4];
  const float* Ws  = (const float*)d_in[5];
  const float* bs  = (const float*)d_in[6];
  const float* Wf  = (const float*)d_in[7];
  const float* bf  = (const float*)d_in[8];
  float* outp = (float*)d_out;
  float* ws   = (float*)d_ws;

  hipLaunchKernelGGL(prep_kernel, dim3(32), dim3(256), 0, stream,
                     Wt, bt, Ws, bs, ws);
  hipLaunchKernelGGL(attn_kernel, dim3(4096), dim3(512), 0, stream,
                     ht, hs, len, Wf, bf, ws, outp);
}

// Round 5
// 215.371 us; speedup vs baseline: 1.3499x; 1.3499x over previous
//
#include <hip/hip_runtime.h>

// dims: S=128, E=256 -> 32768 pairs; H=20, D=64, A=64, NH=8
constexpr float TEMP = 2.5f;    // H / sqrt(A) = 20/8
constexpr float NEGV = -1e9f;

// ---- workspace layout (floats) ----
constexpr int MT_OFF  = 0;      // Mt[n][d][dp]  (transposed, pre-scaled TEMP)
constexpr int K_OFF   = 32768;  // k[8][64]
constexpr int P_OFF   = 33280;  // p[8][64]
constexpr int Q_OFF   = 33792;  // q[8]
constexpr int WFT_OFF = 33800;  // Wft[n][d][dd] (transposed)

// ---- main-kernel LDS layout (floats) ----
constexpr int HS_OFF  = 0;      // hs[8 pairs][20 rows][16 quads] swizzled (10240)
                                //   slot (p,m,qs) holds quad q = qs ^ (m&7)
                                //   after P3 re-used as y[8][8][66] (4224)
constexpr int HT_OFF  = 10240;  // ht[8][64]            (512)
constexpr int V_OFF   = 10752;  // V/wv [8 pairs][520]  (4160)
constexpr int ATT_OFF = 14912;  // attn[8][20][12]      (1920)
constexpr int C_OFF   = 16832;  // c[8 pairs][8 heads]  (64)
constexpr int LEN_OFF = 16896;  // len[8]               (8)
constexpr int LDS_FL  = 16904;  // 67,616 B -> 2 blocks/CU (16 waves/CU)

// ============================================================
// prep (grid 64): blocks 0..31  -> Mt (transposed) + k,p,q
//                 blocks 32..63 -> Wft (transposed)
// ============================================================
__global__ __launch_bounds__(256) void prep_kernel(
    const float* __restrict__ Wt, const float* __restrict__ bt,
    const float* __restrict__ Ws, const float* __restrict__ bs,
    const float* __restrict__ Wf, float* __restrict__ ws) {
  const int t = threadIdx.x;
  if (blockIdx.x >= 32) {                       // ---- Wf transpose ----
    const int b = blockIdx.x - 32;
    const int n = b >> 2, q = b & 3;            // dd range [q*16, q*16+16)
#pragma unroll
    for (int i = 0; i < 4; ++i) {
      const int idx = i * 256 + t;              // 0..1023
      const int ddl = idx >> 6, d = idx & 63;
      ws[WFT_OFF + n * 4096 + d * 64 + q * 16 + ddl] =
          Wf[(n * 64 + q * 16 + ddl) * 64 + d];
    }
    return;
  }
  __shared__ float WsL[64 * 65];
  __shared__ float WtL[16 * 65];
  const int n  = blockIdx.x >> 2;
  const int q  = blockIdx.x & 3;
  const int dp0 = q * 16;
  const float* Wtn = Wt + n * 4096;
  const float* Wsn = Ws + n * 4096;
#pragma unroll
  for (int i = 0; i < 16; ++i) {
    const int idx = i * 256 + t;
    WsL[(idx >> 6) * 65 + (idx & 63)] = Wsn[idx];
  }
#pragma unroll
  for (int i = 0; i < 4; ++i) {
    const int idx = i * 256 + t;
    WtL[(idx >> 6) * 65 + (idx & 63)] = Wtn[dp0 * 64 + idx];
  }
  __syncthreads();
#pragma unroll
  for (int i = 0; i < 4; ++i) {
    const int idx = i * 256 + t;
    const int dpl = idx >> 6, d = idx & 63;
    const float* wtr = &WtL[dpl * 65];
    const float* wsr = &WsL[d * 65];
    float acc = 0.f;
#pragma unroll 8
    for (int a = 0; a < 64; ++a) acc += wtr[a] * wsr[a];
    ws[MT_OFF + n * 4096 + d * 64 + (dp0 + dpl)] = acc * TEMP;   // transposed
  }
  if (q == 0 && t < 64) {
    float acc = 0.f;
#pragma unroll 8
    for (int a = 0; a < 64; ++a) acc += WsL[t * 65 + a] * bt[n * 64 + a];
    ws[K_OFF + n * 64 + t] = acc * TEMP;
  }
  if (t >= 64 && t < 80) {
    const int r = t - 64;
    float acc = 0.f;
#pragma unroll 8
    for (int a = 0; a < 64; ++a) acc += WtL[r * 65 + a] * bs[n * 64 + a];
    ws[P_OFF + n * 64 + dp0 + r] = acc * TEMP;
  }
  if (q == 0 && t == 128) {
    float acc = 0.f;
    for (int a = 0; a < 64; ++a) acc += bt[n * 64 + a] * bs[n * 64 + a];
    ws[Q_OFF + n] = acc * TEMP;
  }
}

// ============================================================
// main: 8 pairs/block, 512 threads (8 waves), grid 4096.
// hs staged ONCE via async global_load_lds (source-swizzled);
// Mt/Wft b128 per-lane-contiguous; hs never re-read from global.
// ============================================================
__global__ __launch_bounds__(512, 4) void attn_kernel(
    const float* __restrict__ ht_g, const float* __restrict__ hs_g,
    const int* __restrict__ len_g, const float* __restrict__ bf,
    const float* __restrict__ wsp, float* __restrict__ out) {
  __shared__ __align__(16) float lds[LDS_FL];
  const int t    = threadIdx.x;
  const int lane = t & 63;
  const int w    = t >> 6;            // wave id 0..7
  const int pair0 = blockIdx.x * 8;

  // ---------- stage ht + len (plain, cross-wave -> barrier A) ----------
  lds[HT_OFF + t] = ht_g[(size_t)pair0 * 64 + t];
  if (t < 8) lds[LEN_OFF + t] = (float)len_g[pair0 + t];
  __syncthreads();   // barrier A (no async loads outstanding yet)

  // ---------- issue async hs staging (lands under V phase) ----------
  // LDS linear in chunk index; global source pre-swizzled: slot (p,m,qs)
  // receives quad q = qs ^ (m&7).
  {
    const int wbase = w * 64;                   // wave-uniform
#pragma unroll
    for (int i = 0; i < 5; ++i) {
      const int c  = i * 512 + t;               // chunk 0..2559
      const int p  = c / 320;
      const int s  = c - p * 320;
      const int m  = s >> 4, qs = s & 15;
      const int q  = qs ^ (m & 7);
      const float* src = hs_g + (size_t)(pair0 + p) * 1280 + m * 64 + q * 4;
      __builtin_amdgcn_global_load_lds(
          (const __attribute__((address_space(1))) void*)src,
          (__attribute__((address_space(3))) void*)&lds[HS_OFF + (i * 512 + wbase) * 4],
          16, 0, 0);
    }
  }

  // ---------- V phase: wave w = head n, lane = d ----------
  // V[p][n][d] = k[n][d] + sum_dp ht[p][dp] * Mt[n][d][dp]
  {
    const int n = w, d = lane;
    float acc[8];
    const float kv = wsp[K_OFF + n * 64 + d];
#pragma unroll
    for (int p = 0; p < 8; ++p) acc[p] = kv;
    const float4* Mt4 = (const float4*)&wsp[MT_OFF + n * 4096 + d * 64];
#pragma unroll
    for (int c = 0; c < 16; ++c) {
      const float4 m4 = Mt4[c];                 // contiguous b128 per lane
#pragma unroll
      for (int p = 0; p < 8; ++p) {
        const float4 h4 = *(const float4*)&lds[HT_OFF + p * 64 + c * 4];
        acc[p] += h4.x * m4.x + h4.y * m4.y + h4.z * m4.z + h4.w * m4.w;
      }
    }
    float* vp = &lds[V_OFF + n * 64 + d];
#pragma unroll
    for (int p = 0; p < 8; ++p) vp[p * 520] = acc[p];
  }

  // ---------- c[p][n] = q[n] + ht·p[n]  (8 lanes of each wave) ----------
  {
    const int n = w;
    if (lane < 8) {
      const float* htp = &lds[HT_OFF + lane * 64];
      float cacc = wsp[Q_OFF + n];
#pragma unroll 8
      for (int dp = 0; dp < 64; ++dp)
        cacc = fmaf(htp[dp], wsp[P_OFF + n * 64 + dp], cacc);
      lds[C_OFF + lane * 8 + n] = cacc;
    }
  }
  __syncthreads();   // barrier 1: V, c visible; drains hs staging (vmcnt 0)

  // ---------- P2: scores + softmax. wave = pair, halves = 4 heads each ----
  {
    const int p  = w;
    const int m_ = lane & 31;
    const int nn = lane >> 5;
    const int mm = (m_ < 20) ? m_ : 19;
    const bool act = (m_ < 20);
    const int mk = mm & 7;
    const float* hsb = &lds[HS_OFF + p * 1280 + mm * 64];
    const float* vb  = &lds[V_OFF + p * 520 + nn * 256];
    float s[4];
#pragma unroll
    for (int it = 0; it < 4; ++it) s[it] = lds[C_OFF + p * 8 + nn * 4 + it];
#pragma unroll
    for (int dq = 0; dq < 16; ++dq) {
      const int qs = dq ^ mk;                    // de-swizzle
      const float4 h4 = *(const float4*)&hsb[qs * 4];
#pragma unroll
      for (int it = 0; it < 4; ++it) {
        const float4 v4 = *(const float4*)&vb[it * 64 + dq * 4];
        s[it] += h4.x * v4.x + h4.y * v4.y + h4.z * v4.z + h4.w * v4.w;
      }
    }
    const int lenp = (int)lds[LEN_OFF + p];
    float at[4];
#pragma unroll
    for (int it = 0; it < 4; ++it) {
      float sv = (act && m_ < lenp) ? s[it] : NEGV;
      float mx = sv;
#pragma unroll
      for (int o = 16; o; o >>= 1) mx = fmaxf(mx, __shfl_xor(mx, o, 32));
      const float e = act ? __expf(sv - mx) : 0.f;
      float sm = e;
#pragma unroll
      for (int o = 16; o; o >>= 1) sm += __shfl_xor(sm, o, 32);
      at[it] = e / sm;
    }
    if (act)
      *(float4*)&lds[ATT_OFF + p * 240 + m_ * 12 + nn * 4] =
          make_float4(at[0], at[1], at[2], at[3]);
  }
  // no barrier: P3 touches only this wave's pair

  // ---------- P3: wv[p][n][d] = sum_m attn[p][m][n]*hs[p][m][d] ----------
  {
    const int p = w, d = lane;
    const int qd = d >> 2, r = d & 3;
    const float* hsb = &lds[HS_OFF + p * 1280];
    float wv[8] = {0.f, 0.f, 0.f, 0.f, 0.f, 0.f, 0.f, 0.f};
    const float* atp = &lds[ATT_OFF + p * 240];
#pragma unroll
    for (int m_ = 0; m_ < 20; ++m_) {
      const float h = hsb[m_ * 64 + ((qd ^ (m_ & 7)) << 2) + r];  // de-swizzle
      const float4 a0 = *(const float4*)&atp[m_ * 12];
      const float4 a1 = *(const float4*)&atp[m_ * 12 + 4];
      wv[0] += a0.x * h; wv[1] += a0.y * h; wv[2] += a0.z * h; wv[3] += a0.w * h;
      wv[4] += a1.x * h; wv[5] += a1.y * h; wv[6] += a1.z * h; wv[7] += a1.w * h;
    }
    float* vd = &lds[V_OFF + p * 520 + d];   // overwrite V (dead after P2)
#pragma unroll
    for (int n = 0; n < 8; ++n) vd[n * 64] = wv[n];
  }
  __syncthreads();   // barrier 2: all pairs' wv visible; hs arena now dead

  // ---------- P4a: y[p][n][d] = sum_dd wv[p][n*64+dd]*Wft[n][d][dd] ------
  {
    const int n = w, d = lane;
    float acc[8] = {0.f, 0.f, 0.f, 0.f, 0.f, 0.f, 0.f, 0.f};
    const float4* Wf4 = (const float4*)&wsp[WFT_OFF + n * 4096 + d * 64];
#pragma unroll
    for (int c = 0; c < 16; ++c) {
      const float4 wq = Wf4[c];                 // contiguous b128 per lane
#pragma unroll
      for (int p = 0; p < 8; ++p) {
        const float4 w4 = *(const float4*)&lds[V_OFF + p * 520 + n * 64 + c * 4];
        acc[p] += w4.x * wq.x + w4.y * wq.y + w4.z * wq.z + w4.w * wq.w;
      }
    }
#pragma unroll
    for (int p = 0; p < 8; ++p)
      lds[HS_OFF + p * 528 + n * 66 + d] = acc[p];   // y into dead hs arena
  }
  __syncthreads();   // barrier 3

  // ---------- P4b: out[p][d] = bf[d] + sum_n y[p][n][d] ----------
  {
    const int p = t >> 6, d = t & 63;
    float o = bf[d];
#pragma unroll
    for (int n = 0; n < 8; ++n) o += lds[HS_OFF + p * 528 + n * 66 + d];
    out[(size_t)pair0 * 64 + t] = o;
  }
}

extern "C" void kernel_launch(void* const* d_in, const int* in_sizes, int n_in,
                              void* d_out, int out_size, void* d_ws, size_t ws_size,
                              hipStream_t stream) {
  const float* ht  = (const float*)d_in[0];
  const float* hs  = (const float*)d_in[1];
  const int*   len = (const int*)d_in[2];
  const float* Wt  = (const float*)d_in[3];
  const float* bt  = (const float*)d_in[4];
  const float* Ws  = (const float*)d_in[5];
  const float* bs  = (const float*)d_in[6];
  const float* Wf  = (const float*)d_in[7];
  const float* bf  = (const float*)d_in[8];
  float* outp = (float*)d_out;
  float* ws   = (float*)d_ws;

  hipLaunchKernelGGL(prep_kernel, dim3(64), dim3(256), 0, stream,
                     Wt, bt, Ws, bs, Wf, ws);
  hipLaunchKernelGGL(attn_kernel, dim3(4096), dim3(512), 0, stream,
                     ht, hs, len, bf, ws, outp);
}

// Round 6
// 148.130 us; speedup vs baseline: 1.9627x; 1.4539x over previous
//
#include <hip/hip_runtime.h>

typedef __attribute__((ext_vector_type(8))) short short8;
typedef __attribute__((ext_vector_type(4))) float f32x4;

// dims: S=128, E=256 -> 32768 pairs; H=20, D=64, A=64, NH=8
constexpr float TEMP = 2.5f;    // H / sqrt(A) = 20/8
constexpr float NEGV = -1e9f;

// ---- workspace layout (dwords) ----
constexpr int K_OFF  = 0;       // k[8][64] f32 (TEMP-scaled)
constexpr int P_OFF  = 512;     // p[8][64] f32 (TEMP-scaled)
constexpr int Q_OFF  = 1024;    // q[8]     f32 (TEMP-scaled)
constexpr int MFRAG  = 1040;    // M  B-frags [8 n][2 ks][4 dt][3 s][64 lane][4 dw]
constexpr int WFRAG  = MFRAG + 8 * 6144;   // Wf B-frags, same shape
// total 99344 dw = 397 KB

// ---- main-kernel LDS layout (floats) ----
constexpr int HS_OFF  = 0;      // hs[8][20][16 quads] swizzled (10240)
                                //   after P3: wv3 bf16 [3][8][520] (6236 fl) + y
constexpr int Y_OFF   = 6240;   // y[2 ng][8 p][64 d] (1024 fl, inside hs arena)
constexpr int HT_OFF  = 10240;  // ht fp32 [8][64]      (512)
constexpr int HT3_OFF = 10752;  // ht bf16 splits [3][16][80] (1920 fl)
constexpr int V_OFF   = 12672;  // V/wv [8 p][520]      (4160)
constexpr int ATT_OFF = 16832;  // attn[8][20][12]      (1920)
constexpr int C_OFF   = 18752;  // c[8 p][8 n]          (64)
constexpr int LEN_OFF = 18816;  // len[8]               (8)
constexpr int LDS_FL  = 18824;  // 75,296 B -> 2 blocks/CU

#define MFMA_B16 __builtin_amdgcn_mfma_f32_16x16x32_bf16

// ---- bf16 split helpers (RNE truncation) ----
__device__ inline ushort bf16_rne(float x) {
  uint u = __float_as_uint(x);
  u += 0x7FFF + ((u >> 16) & 1);
  return (ushort)(u >> 16);
}
__device__ inline float bf16_f(ushort h) { return __uint_as_float(((uint)h) << 16); }
__device__ inline void split3(float x, ushort& h0, ushort& h1, ushort& h2) {
  h0 = bf16_rne(x); float f0 = bf16_f(h0);
  float r = x - f0;
  h1 = bf16_rne(r); float f1 = bf16_f(h1);
  h2 = bf16_rne(r - f1);
}
__device__ inline ushort split_lvl(float x, int s) {
  ushort a, b, c; split3(x, a, b, c);
  return s == 0 ? a : (s == 1 ? b : c);
}

// ============================================================
// prep (grid 16): blocks 0..7  -> M[n] + k,p,q + M B-frags (3-way split)
//                 blocks 8..15 -> Wf[n] B-frags (3-way split)
// B-frag layout per (n,ks,dt,s): lane holds cols d=dt*16+(l&15),
// k = ks*32+(l>>4)*8+2r (+1) packed into 4 dwords -> one b128/lane.
// ============================================================
__global__ __launch_bounds__(256) void prep_kernel(
    const float* __restrict__ Wt, const float* __restrict__ bt,
    const float* __restrict__ Ws, const float* __restrict__ bs,
    const float* __restrict__ Wf, float* __restrict__ ws) {
  __shared__ float AL[64 * 65];
  __shared__ float BL[64 * 65];
  __shared__ float ML[64 * 65];
  const int t = threadIdx.x;
  uint* wsu = (uint*)ws;
  if (blockIdx.x < 8) {
    const int n = blockIdx.x;
#pragma unroll
    for (int i = 0; i < 16; ++i) {
      int idx = i * 256 + t;
      AL[(idx >> 6) * 65 + (idx & 63)] = Wt[n * 4096 + idx];
      BL[(idx >> 6) * 65 + (idx & 63)] = Ws[n * 4096 + idx];
    }
    __syncthreads();
#pragma unroll
    for (int i = 0; i < 16; ++i) {            // M[dp][d] = Wt[dp]·Ws[d] * TEMP
      int idx = i * 256 + t;
      int dp = idx >> 6, d = idx & 63;
      float acc = 0.f;
#pragma unroll 8
      for (int a = 0; a < 64; ++a) acc += AL[dp * 65 + a] * BL[d * 65 + a];
      ML[dp * 65 + d] = acc * TEMP;
    }
    if (t < 64) {                             // k[d] = Ws[d]·bt * TEMP
      float acc = 0.f;
#pragma unroll 8
      for (int a = 0; a < 64; ++a) acc += BL[t * 65 + a] * bt[n * 64 + a];
      ws[K_OFF + n * 64 + t] = acc * TEMP;
    } else if (t < 128) {                     // p[dp] = Wt[dp]·bs * TEMP
      int r = t - 64;
      float acc = 0.f;
#pragma unroll 8
      for (int a = 0; a < 64; ++a) acc += AL[r * 65 + a] * bs[n * 64 + a];
      ws[P_OFF + n * 64 + r] = acc * TEMP;
    } else if (t == 128) {                    // q = bt·bs * TEMP
      float acc = 0.f;
      for (int a = 0; a < 64; ++a) acc += bt[n * 64 + a] * bs[n * 64 + a];
      ws[Q_OFF + n] = acc * TEMP;
    }
    __syncthreads();
#pragma unroll
    for (int i = 0; i < 24; ++i) {            // 6144 frag dwords
      int f = i * 256 + t;
      int r = f & 3, lane = (f >> 2) & 63, rest = f >> 8;
      int s = rest % 3, rest2 = rest / 3, dt = rest2 & 3, ks = rest2 >> 2;
      int k = ks * 32 + ((lane >> 4) & 3) * 8 + r * 2;
      int d = dt * 16 + (lane & 15);
      uint lo = split_lvl(ML[k * 65 + d], s);
      uint hi = split_lvl(ML[(k + 1) * 65 + d], s);
      wsu[MFRAG + n * 6144 + (((ks * 4 + dt) * 3 + s) * 64 + lane) * 4 + r] =
          lo | (hi << 16);
    }
  } else {
    const int n = blockIdx.x - 8;
#pragma unroll
    for (int i = 0; i < 16; ++i) {            // Wf slice rows n*64.. (k=dd, col=d)
      int idx = i * 256 + t;
      AL[(idx >> 6) * 65 + (idx & 63)] = Wf[(n * 64 + (idx >> 6)) * 64 + (idx & 63)];
    }
    __syncthreads();
#pragma unroll
    for (int i = 0; i < 24; ++i) {
      int f = i * 256 + t;
      int r = f & 3, lane = (f >> 2) & 63, rest = f >> 8;
      int s = rest % 3, rest2 = rest / 3, dt = rest2 & 3, ks = rest2 >> 2;
      int k = ks * 32 + ((lane >> 4) & 3) * 8 + r * 2;
      int d = dt * 16 + (lane & 15);
      uint lo = split_lvl(AL[k * 65 + d], s);
      uint hi = split_lvl(AL[(k + 1) * 65 + d], s);
      wsu[WFRAG + n * 6144 + (((ks * 4 + dt) * 3 + s) * 64 + lane) * 4 + r] =
          lo | (hi << 16);
    }
  }
}

// 6-term split-product MFMA cluster for one (dt): error ~2^-26 relative
#define SPLIT_MFMA(FB, STRIDE_DT, CC)                                          \
  {                                                                            \
    short8 b00 = *(const short8*)&(FB)[(0 * 4 + (STRIDE_DT)) * 768 + 0 * 256]; \
    short8 b01 = *(const short8*)&(FB)[(0 * 4 + (STRIDE_DT)) * 768 + 1 * 256]; \
    short8 b02 = *(const short8*)&(FB)[(0 * 4 + (STRIDE_DT)) * 768 + 2 * 256]; \
    short8 b10 = *(const short8*)&(FB)[(1 * 4 + (STRIDE_DT)) * 768 + 0 * 256]; \
    short8 b11 = *(const short8*)&(FB)[(1 * 4 + (STRIDE_DT)) * 768 + 1 * 256]; \
    short8 b12 = *(const short8*)&(FB)[(1 * 4 + (STRIDE_DT)) * 768 + 2 * 256]; \
    CC = MFMA_B16(a00, b00, CC, 0, 0, 0);                                      \
    CC = MFMA_B16(a00, b01, CC, 0, 0, 0);                                      \
    CC = MFMA_B16(a01, b00, CC, 0, 0, 0);                                      \
    CC = MFMA_B16(a00, b02, CC, 0, 0, 0);                                      \
    CC = MFMA_B16(a01, b01, CC, 0, 0, 0);                                      \
    CC = MFMA_B16(a02, b00, CC, 0, 0, 0);                                      \
    CC = MFMA_B16(a10, b10, CC, 0, 0, 0);                                      \
    CC = MFMA_B16(a10, b11, CC, 0, 0, 0);                                      \
    CC = MFMA_B16(a11, b10, CC, 0, 0, 0);                                      \
    CC = MFMA_B16(a10, b12, CC, 0, 0, 0);                                      \
    CC = MFMA_B16(a11, b11, CC, 0, 0, 0);                                      \
    CC = MFMA_B16(a12, b10, CC, 0, 0, 0);                                      \
  }

// ============================================================
// main: 8 pairs/block (padded to 16 MFMA rows), 512 threads, grid 4096.
// ============================================================
__global__ __launch_bounds__(512, 4) void attn_kernel(
    const float* __restrict__ ht_g, const float* __restrict__ hs_g,
    const int* __restrict__ len_g, const float* __restrict__ bf,
    const float* __restrict__ wsp, float* __restrict__ out) {
  __shared__ __align__(16) float lds[LDS_FL];
  const int t    = threadIdx.x;
  const int lane = t & 63;
  const int w    = t >> 6;
  const int pair0 = blockIdx.x * 8;
  ushort* ht3 = (ushort*)&lds[HT3_OFF];
  const uint* wsu = (const uint*)wsp;

  // ---------- stage ht + 3-way split + len ----------
  {
    float x = ht_g[(size_t)pair0 * 64 + t];
    lds[HT_OFF + t] = x;
    ushort h0, h1, h2; split3(x, h0, h1, h2);
    const int p = t >> 6, dp = t & 63;       // rows 8..15 left as don't-care
    ht3[0 * 1280 + p * 80 + dp] = h0;
    ht3[1 * 1280 + p * 80 + dp] = h1;
    ht3[2 * 1280 + p * 80 + dp] = h2;
  }
  if (t < 8) lds[LEN_OFF + t] = (float)len_g[pair0 + t];
  __syncthreads();   // barrier A: ht/ht3 visible

  // ---------- issue async hs staging (R5-verified, lands by barrier 1) ----
  {
#pragma unroll
    for (int i = 0; i < 5; ++i) {
      const int c  = i * 512 + t;
      const int p  = c / 320;
      const int s  = c - p * 320;
      const int m  = s >> 4, qs = s & 15;
      const int q  = qs ^ (m & 7);
      const float* src = hs_g + (size_t)(pair0 + p) * 1280 + m * 64 + q * 4;
      __builtin_amdgcn_global_load_lds(
          (const __attribute__((address_space(1))) void*)src,
          (__attribute__((address_space(3))) void*)&lds[HS_OFF + (i * 512 + w * 64) * 4],
          16, 0, 0);
    }
  }

  // ---------- V phase (MFMA): wave = head n ----------
  // V[p][n][d] = k[n][d] + sum_dp ht[p][dp]*M[n][dp][d]
  {
    const int n = w, lo4 = lane & 15, kg = lane >> 4;
    short8 a00 = *(const short8*)&ht3[0 * 1280 + lo4 * 80 + 0  + kg * 8];
    short8 a01 = *(const short8*)&ht3[1 * 1280 + lo4 * 80 + 0  + kg * 8];
    short8 a02 = *(const short8*)&ht3[2 * 1280 + lo4 * 80 + 0  + kg * 8];
    short8 a10 = *(const short8*)&ht3[0 * 1280 + lo4 * 80 + 32 + kg * 8];
    short8 a11 = *(const short8*)&ht3[1 * 1280 + lo4 * 80 + 32 + kg * 8];
    short8 a12 = *(const short8*)&ht3[2 * 1280 + lo4 * 80 + 32 + kg * 8];
    const uint* fb = wsu + MFRAG + n * 6144 + lane * 4;
    const float* kb = &wsp[K_OFF + n * 64 + lo4];
    float kv0 = kb[0], kv1 = kb[16], kv2 = kb[32], kv3 = kb[48];
    f32x4 c0 = {kv0, kv0, kv0, kv0};
    f32x4 c1 = {kv1, kv1, kv1, kv1};
    f32x4 c2 = {kv2, kv2, kv2, kv2};
    f32x4 c3 = {kv3, kv3, kv3, kv3};
    SPLIT_MFMA(fb, 0, c0)
    SPLIT_MFMA(fb, 1, c1)
    SPLIT_MFMA(fb, 2, c2)
    SPLIT_MFMA(fb, 3, c3)
    if (kg < 2) {                            // rows 0..7 real
#pragma unroll
      for (int reg = 0; reg < 4; ++reg) {
        const int p = kg * 4 + reg;
        lds[V_OFF + p * 520 + n * 64 +  0 + lo4] = c0[reg];
        lds[V_OFF + p * 520 + n * 64 + 16 + lo4] = c1[reg];
        lds[V_OFF + p * 520 + n * 64 + 32 + lo4] = c2[reg];
        lds[V_OFF + p * 520 + n * 64 + 48 + lo4] = c3[reg];
      }
    }
  }

  // ---------- c[p][n] = q[n] + ht·p[n] ----------
  {
    const int n = w;
    if (lane < 8) {
      const float* htp = &lds[HT_OFF + lane * 64];
      float cacc = wsp[Q_OFF + n];
#pragma unroll 8
      for (int dp = 0; dp < 64; ++dp)
        cacc = fmaf(htp[dp], wsp[P_OFF + n * 64 + dp], cacc);
      lds[C_OFF + lane * 8 + n] = cacc;
    }
  }
  __syncthreads();   // barrier 1: V, c visible; hs staging drained

  // ---------- P2: scores + softmax (R5-verified) ----------
  {
    const int p  = w;
    const int m_ = lane & 31;
    const int nn = lane >> 5;
    const int mm = (m_ < 20) ? m_ : 19;
    const bool act = (m_ < 20);
    const int mk = mm & 7;
    const float* hsb = &lds[HS_OFF + p * 1280 + mm * 64];
    const float* vb  = &lds[V_OFF + p * 520 + nn * 256];
    float s[4];
#pragma unroll
    for (int it = 0; it < 4; ++it) s[it] = lds[C_OFF + p * 8 + nn * 4 + it];
#pragma unroll
    for (int dq = 0; dq < 16; ++dq) {
      const int qs = dq ^ mk;
      const float4 h4 = *(const float4*)&hsb[qs * 4];
#pragma unroll
      for (int it = 0; it < 4; ++it) {
        const float4 v4 = *(const float4*)&vb[it * 64 + dq * 4];
        s[it] += h4.x * v4.x + h4.y * v4.y + h4.z * v4.z + h4.w * v4.w;
      }
    }
    const int lenp = (int)lds[LEN_OFF + p];
    float at[4];
#pragma unroll
    for (int it = 0; it < 4; ++it) {
      float sv = (act && m_ < lenp) ? s[it] : NEGV;
      float mx = sv;
#pragma unroll
      for (int o = 16; o; o >>= 1) mx = fmaxf(mx, __shfl_xor(mx, o, 32));
      const float e = act ? __expf(sv - mx) : 0.f;
      float sm = e;
#pragma unroll
      for (int o = 16; o; o >>= 1) sm += __shfl_xor(sm, o, 32);
      at[it] = e / sm;
    }
    if (act)
      *(float4*)&lds[ATT_OFF + p * 240 + m_ * 12 + nn * 4] =
          make_float4(at[0], at[1], at[2], at[3]);
  }
  // no barrier: P3 pair-local

  // ---------- P3: wv[p][n][d] = sum_m attn*hs (R5-verified) ----------
  {
    const int p = w, d = lane;
    const int qd = d >> 2, r = d & 3;
    const float* hsb = &lds[HS_OFF + p * 1280];
    float wv[8] = {0.f, 0.f, 0.f, 0.f, 0.f, 0.f, 0.f, 0.f};
    const float* atp = &lds[ATT_OFF + p * 240];
#pragma unroll
    for (int m_ = 0; m_ < 20; ++m_) {
      const float h = hsb[m_ * 64 + ((qd ^ (m_ & 7)) << 2) + r];
      const float4 a0 = *(const float4*)&atp[m_ * 12];
      const float4 a1 = *(const float4*)&atp[m_ * 12 + 4];
      wv[0] += a0.x * h; wv[1] += a0.y * h; wv[2] += a0.z * h; wv[3] += a0.w * h;
      wv[4] += a1.x * h; wv[5] += a1.y * h; wv[6] += a1.z * h; wv[7] += a1.w * h;
    }
    float* vd = &lds[V_OFF + p * 520 + d];
#pragma unroll
    for (int n = 0; n < 8; ++n) vd[n * 64] = wv[n];
  }
  __syncthreads();   // barrier 2: wv visible; hs arena dead

  // ---------- wv -> 3-way bf16 split into dead hs arena ----------
  {
    ushort* wv3 = (ushort*)&lds[HS_OFF];
#pragma unroll
    for (int i = 0; i < 8; ++i) {
      const int idx = i * 512 + t;             // 0..4095
      const int p = idx >> 9, dd = idx & 511;
      float x = lds[V_OFF + p * 520 + dd];
      ushort h0, h1, h2; split3(x, h0, h1, h2);
      wv3[0 * 4160 + p * 520 + dd] = h0;
      wv3[1 * 4160 + p * 520 + dd] = h1;
      wv3[2 * 4160 + p * 520 + dd] = h2;
    }
  }
  __syncthreads();   // barrier 2b: wv3 visible

  // ---------- P4a (MFMA): wave (dt = w&3, ng = w>>2) ----------
  // y[p][dt*16+col] = sum_{n in ng} sum_dd wv[p][n*64+dd]*Wf[n*64+dd][d]
  {
    const int dt = w & 3, ng = w >> 2;
    const int lo4 = lane & 15, kg = lane >> 4;
    const ushort* wv3 = (const ushort*)&lds[HS_OFF];
    f32x4 cc = {0.f, 0.f, 0.f, 0.f};
#pragma unroll
    for (int nn = 0; nn < 4; ++nn) {
      const int n = ng * 4 + nn;
      short8 a00 = *(const short8*)&wv3[0 * 4160 + lo4 * 520 + n * 64 + 0  + kg * 8];
      short8 a01 = *(const short8*)&wv3[1 * 4160 + lo4 * 520 + n * 64 + 0  + kg * 8];
      short8 a02 = *(const short8*)&wv3[2 * 4160 + lo4 * 520 + n * 64 + 0  + kg * 8];
      short8 a10 = *(const short8*)&wv3[0 * 4160 + lo4 * 520 + n * 64 + 32 + kg * 8];
      short8 a11 = *(const short8*)&wv3[1 * 4160 + lo4 * 520 + n * 64 + 32 + kg * 8];
      short8 a12 = *(const short8*)&wv3[2 * 4160 + lo4 * 520 + n * 64 + 32 + kg * 8];
      const uint* fb = wsu + WFRAG + n * 6144 + lane * 4;
      SPLIT_MFMA(fb, dt, cc)
    }
    if (kg < 2) {
#pragma unroll
      for (int reg = 0; reg < 4; ++reg)
        lds[Y_OFF + ng * 512 + (kg * 4 + reg) * 64 + dt * 16 + lo4] = cc[reg];
    }
  }
  __syncthreads();   // barrier 3

  // ---------- P4b: out = bf + y0 + y1 ----------
  {
    const int d = t & 63;
    out[(size_t)pair0 * 64 + t] =
        bf[d] + lds[Y_OFF + t] + lds[Y_OFF + 512 + t];
  }
}

extern "C" void kernel_launch(void* const* d_in, const int* in_sizes, int n_in,
                              void* d_out, int out_size, void* d_ws, size_t ws_size,
                              hipStream_t stream) {
  const float* ht  = (const float*)d_in[0];
  const float* hs  = (const float*)d_in[1];
  const int*   len = (const int*)d_in[2];
  const float* Wt  = (const float*)d_in[3];
  const float* bt  = (const float*)d_in[4];
  const float* Ws  = (const float*)d_in[5];
  const float* bs  = (const float*)d_in[6];
  const float* Wf  = (const float*)d_in[7];
  const float* bf  = (const float*)d_in[8];
  float* outp = (float*)d_out;
  float* ws   = (float*)d_ws;

  hipLaunchKernelGGL(prep_kernel, dim3(16), dim3(256), 0, stream,
                     Wt, bt, Ws, bs, Wf, ws);
  hipLaunchKernelGGL(attn_kernel, dim3(4096), dim3(512), 0, stream,
                     ht, hs, len, bf, ws, outp);
}

// Round 7
// 112.627 us; speedup vs baseline: 2.5814x; 1.3152x over previous
//
#include <hip/hip_runtime.h>

typedef __attribute__((ext_vector_type(8))) short short8;
typedef __attribute__((ext_vector_type(4))) float f32x4;

// dims: S=128, E=256 -> 32768 pairs; H=20, D=64, A=64, NH=8
constexpr float TEMP = 2.5f;    // H / sqrt(A) = 20/8
constexpr float NEGV = -1e9f;

// ---- workspace layout (dwords) ----
constexpr int K_OFF  = 0;       // k[8][64] f32 (TEMP-scaled)
constexpr int P_OFF  = 512;     // p[8][64] f32 (TEMP-scaled, unused by attn now)
constexpr int Q_OFF  = 1024;    // q[8]     f32 (TEMP-scaled)
constexpr int PFRAG  = 1040;    // P  B-frags [2 ks][2 s][64 lane][4 dw] (1024)
constexpr int MFRAG  = 2064;    // M  B-frags [8 n][2 ks][4 dt][2 s][64][4] (32768)
constexpr int WFRAG  = 34832;   // Wf B-frags, same shape (32768)

// ---- main-kernel LDS layout (floats) ----
constexpr int HS_OFF  = 0;      // hs[8][20][16 quads] swizzled (10240)
                                //   after barrier 2: y[2 ng][8 p][64 d] @0
constexpr int HT_OFF  = 10240;  // ht fp32 [8][64]          (512)
constexpr int HT2_OFF = 10752;  // ht bf16 2-way [2][8][80]u (640)
constexpr int V_OFF   = 11392;  // V fp32 [8 p][520] ; after P2(wave-local):
                                //   wv2 bf16 [p][2 s][520]u  (4160)
constexpr int ATT_OFF = 15552;  // attn[8][20][12]          (1920)
constexpr int C_OFF   = 17472;  // c[8 p][8 n]              (64)
constexpr int LEN_OFF = 17536;  // len[8]                   (8)
constexpr int LDS_FL  = 17544;  // 70,176 B -> 2 blocks/CU

#define MFMA_B16 __builtin_amdgcn_mfma_f32_16x16x32_bf16

// ---- bf16 2-way split helpers (RNE) ----
__device__ inline ushort bf16_rne(float x) {
  uint u = __float_as_uint(x);
  u += 0x7FFF + ((u >> 16) & 1);
  return (ushort)(u >> 16);
}
__device__ inline float bf16_f(ushort h) { return __uint_as_float(((uint)h) << 16); }
__device__ inline void split2(float x, ushort& h0, ushort& h1) {
  h0 = bf16_rne(x);
  h1 = bf16_rne(x - bf16_f(h0));
}
__device__ inline ushort split_lvl2(float x, int s) {
  ushort h0 = bf16_rne(x);
  return s == 0 ? h0 : bf16_rne(x - bf16_f(h0));
}

// ============================================================
// prep (grid 17): 0..7 -> M[n] frags + k,p,q ; 8..15 -> Wf frags ;
//                 16 -> P frags (recomputes p from Wt,bs).
// B-frag (16x16x32): lane l dword r = B[ks*32+((l>>4)&3)*8+2r][col]
//                    | B[..+2r+1]<<16, col = dt*16+(l&15).
// ============================================================
__global__ __launch_bounds__(256) void prep_kernel(
    const float* __restrict__ Wt, const float* __restrict__ bt,
    const float* __restrict__ Ws, const float* __restrict__ bs,
    const float* __restrict__ Wf, float* __restrict__ ws) {
  __shared__ float AL[64 * 65];
  __shared__ float BL[64 * 65];
  __shared__ float ML[64 * 65];
  const int t = threadIdx.x;
  uint* wsu = (uint*)ws;
  if (blockIdx.x < 8) {
    const int n = blockIdx.x;
#pragma unroll
    for (int i = 0; i < 16; ++i) {
      int idx = i * 256 + t;
      AL[(idx >> 6) * 65 + (idx & 63)] = Wt[n * 4096 + idx];
      BL[(idx >> 6) * 65 + (idx & 63)] = Ws[n * 4096 + idx];
    }
    __syncthreads();
#pragma unroll
    for (int i = 0; i < 16; ++i) {            // M[dp][d] = Wt[dp]·Ws[d] * TEMP
      int idx = i * 256 + t;
      int dp = idx >> 6, d = idx & 63;
      float acc = 0.f;
#pragma unroll 8
      for (int a = 0; a < 64; ++a) acc += AL[dp * 65 + a] * BL[d * 65 + a];
      ML[dp * 65 + d] = acc * TEMP;
    }
    if (t < 64) {
      float acc = 0.f;
#pragma unroll 8
      for (int a = 0; a < 64; ++a) acc += BL[t * 65 + a] * bt[n * 64 + a];
      ws[K_OFF + n * 64 + t] = acc * TEMP;
    } else if (t < 128) {
      int r = t - 64;
      float acc = 0.f;
#pragma unroll 8
      for (int a = 0; a < 64; ++a) acc += AL[r * 65 + a] * bs[n * 64 + a];
      ws[P_OFF + n * 64 + r] = acc * TEMP;
    } else if (t == 128) {
      float acc = 0.f;
      for (int a = 0; a < 64; ++a) acc += bt[n * 64 + a] * bs[n * 64 + a];
      ws[Q_OFF + n] = acc * TEMP;
    }
    __syncthreads();
#pragma unroll
    for (int i = 0; i < 16; ++i) {            // 4096 frag dwords (2-way split)
      int f = i * 256 + t;
      int r = f & 3, lane = (f >> 2) & 63, g = f >> 8;
      int s = g & 1, dt = (g >> 1) & 3, ks = g >> 3;
      int k = ks * 32 + ((lane >> 4) & 3) * 8 + r * 2;
      int d = dt * 16 + (lane & 15);
      uint lo = split_lvl2(ML[k * 65 + d], s);
      uint hi = split_lvl2(ML[(k + 1) * 65 + d], s);
      wsu[MFRAG + n * 4096 + (((ks * 4 + dt) * 2 + s) * 64 + lane) * 4 + r] =
          lo | (hi << 16);
    }
  } else if (blockIdx.x < 16) {
    const int n = blockIdx.x - 8;
#pragma unroll
    for (int i = 0; i < 16; ++i) {            // Wf rows n*64.. (k=dd, col=d)
      int idx = i * 256 + t;
      AL[(idx >> 6) * 65 + (idx & 63)] = Wf[(n * 64 + (idx >> 6)) * 64 + (idx & 63)];
    }
    __syncthreads();
#pragma unroll
    for (int i = 0; i < 16; ++i) {
      int f = i * 256 + t;
      int r = f & 3, lane = (f >> 2) & 63, g = f >> 8;
      int s = g & 1, dt = (g >> 1) & 3, ks = g >> 3;
      int k = ks * 32 + ((lane >> 4) & 3) * 8 + r * 2;
      int d = dt * 16 + (lane & 15);
      uint lo = split_lvl2(AL[k * 65 + d], s);
      uint hi = split_lvl2(AL[(k + 1) * 65 + d], s);
      wsu[WFRAG + n * 4096 + (((ks * 4 + dt) * 2 + s) * 64 + lane) * 4 + r] =
          lo | (hi << 16);
    }
  } else {
    // ---- P frags: p[n][dp] = TEMP * sum_a Wt[n][dp][a]*bs[n][a] ----
#pragma unroll
    for (int i = 0; i < 2; ++i) {
      int idx = i * 256 + t;                  // 0..511
      int n = idx >> 6, dp = idx & 63;
      float acc = 0.f;
#pragma unroll 8
      for (int a = 0; a < 64; ++a)
        acc += Wt[n * 4096 + dp * 64 + a] * bs[n * 64 + a];
      AL[idx] = acc * TEMP;                   // pL[n][dp]
    }
    __syncthreads();
#pragma unroll
    for (int i = 0; i < 4; ++i) {             // 1024 frag dwords
      int f = i * 256 + t;
      int r = f & 3, lane = (f >> 2) & 63, g = f >> 8;   // g 0..3
      int s = g & 1, ks = g >> 1;
      int k = ks * 32 + ((lane >> 4) & 3) * 8 + r * 2;
      int col = lane & 15;
      uint lo = (col < 8) ? (uint)split_lvl2(AL[col * 64 + k], s) : 0u;
      uint hi = (col < 8) ? (uint)split_lvl2(AL[col * 64 + k + 1], s) : 0u;
      wsu[PFRAG + ((ks * 2 + s) * 64 + lane) * 4 + r] = lo | (hi << 16);
    }
  }
}

// 2-way split-product cluster (drops a1*b1 ~2^-18 rel): 6 MFMAs, 4 b-reads
#define SPLIT2_MFMA(FB, DT, CC)                                      \
  {                                                                  \
    short8 b00 = *(const short8*)&(FB)[((0 * 4 + (DT)) * 2 + 0) * 256]; \
    short8 b01 = *(const short8*)&(FB)[((0 * 4 + (DT)) * 2 + 1) * 256]; \
    short8 b10 = *(const short8*)&(FB)[((1 * 4 + (DT)) * 2 + 0) * 256]; \
    short8 b11 = *(const short8*)&(FB)[((1 * 4 + (DT)) * 2 + 1) * 256]; \
    CC = MFMA_B16(a00, b00, CC, 0, 0, 0);                            \
    CC = MFMA_B16(a10, b10, CC, 0, 0, 0);                            \
    CC = MFMA_B16(a00, b01, CC, 0, 0, 0);                            \
    CC = MFMA_B16(a01, b00, CC, 0, 0, 0);                            \
    CC = MFMA_B16(a10, b11, CC, 0, 0, 0);                            \
    CC = MFMA_B16(a11, b10, CC, 0, 0, 0);                            \
  }

// A-frag loads from ht2/wv2 (rows clamped to 8 real pairs)
#define LOAD_A(BASEU, ROWSTR, PLANESTR, ROW, KOFF)                   \
  short8 a00 = *(const short8*)&(BASEU)[(ROW) * (ROWSTR) + (KOFF)];               \
  short8 a01 = *(const short8*)&(BASEU)[(PLANESTR) + (ROW) * (ROWSTR) + (KOFF)];  \
  short8 a10 = *(const short8*)&(BASEU)[(ROW) * (ROWSTR) + 32 + (KOFF)];          \
  short8 a11 = *(const short8*)&(BASEU)[(PLANESTR) + (ROW) * (ROWSTR) + 32 + (KOFF)];

// ============================================================
// main: 8 pairs/block, 512 threads (8 waves), grid 4096.
// ============================================================
__global__ __launch_bounds__(512, 4) void attn_kernel(
    const float* __restrict__ ht_g, const float* __restrict__ hs_g,
    const int* __restrict__ len_g, const float* __restrict__ bf,
    const float* __restrict__ wsp, float* __restrict__ out) {
  __shared__ __align__(16) float lds[LDS_FL];
  const int t    = threadIdx.x;
  const int lane = t & 63;
  const int w    = t >> 6;
  const int pair0 = blockIdx.x * 8;
  ushort* ht2u = (ushort*)&lds[HT2_OFF];
  const uint* wsu = (const uint*)wsp;

  // ---------- stage ht + 2-way split + len ----------
  {
    float x = ht_g[(size_t)pair0 * 64 + t];
    lds[HT_OFF + t] = x;
    ushort h0, h1; split2(x, h0, h1);
    const int p = t >> 6, dp = t & 63;        // ht2 [2 s][8 p][80]u
    ht2u[0 * 640 + p * 80 + dp] = h0;
    ht2u[1 * 640 + p * 80 + dp] = h1;
  }
  if (t < 8) lds[LEN_OFF + t] = (float)len_g[pair0 + t];
  __syncthreads();   // barrier A: ht/ht2 visible

  // ---------- issue async hs staging (verified; lands by barrier 1) ------
  {
#pragma unroll
    for (int i = 0; i < 5; ++i) {
      const int c  = i * 512 + t;
      const int p  = c / 320;
      const int s  = c - p * 320;
      const int m  = s >> 4, qs = s & 15;
      const int q  = qs ^ (m & 7);
      const float* src = hs_g + (size_t)(pair0 + p) * 1280 + m * 64 + q * 4;
      __builtin_amdgcn_global_load_lds(
          (const __attribute__((address_space(1))) void*)src,
          (__attribute__((address_space(3))) void*)&lds[HS_OFF + (i * 512 + w * 64) * 4],
          16, 0, 0);
    }
  }

  const int lo4 = lane & 15, kg = lane >> 4;
  const int rp8 = lo4 & 7;

  // ---------- V phase (MFMA): wave = head n ----------
  {
    const int n = w;
    LOAD_A(ht2u, 80, 640, rp8, kg * 8)
    const uint* fb = wsu + MFRAG + n * 4096 + lane * 4;
    const float* kb = &wsp[K_OFF + n * 64 + lo4];
    float kv0 = kb[0], kv1 = kb[16], kv2 = kb[32], kv3 = kb[48];
    f32x4 c0 = {kv0, kv0, kv0, kv0};
    f32x4 c1 = {kv1, kv1, kv1, kv1};
    f32x4 c2 = {kv2, kv2, kv2, kv2};
    f32x4 c3 = {kv3, kv3, kv3, kv3};
    SPLIT2_MFMA(fb, 0, c0)
    SPLIT2_MFMA(fb, 1, c1)
    SPLIT2_MFMA(fb, 2, c2)
    SPLIT2_MFMA(fb, 3, c3)
    if (kg < 2) {
#pragma unroll
      for (int reg = 0; reg < 4; ++reg) {
        const int p = kg * 4 + reg;
        lds[V_OFF + p * 520 + n * 64 +  0 + lo4] = c0[reg];
        lds[V_OFF + p * 520 + n * 64 + 16 + lo4] = c1[reg];
        lds[V_OFF + p * 520 + n * 64 + 32 + lo4] = c2[reg];
        lds[V_OFF + p * 520 + n * 64 + 48 + lo4] = c3[reg];
      }
    }
  }

  // ---------- c (MFMA, wave 0): c[p][n] = q[n] + ht_p·p_n ----------
  if (w == 0) {
    LOAD_A(ht2u, 80, 640, rp8, kg * 8)
    const uint* fbp = wsu + PFRAG + lane * 4;
    short8 b00 = *(const short8*)&fbp[0 * 256];   // ks0 s0
    short8 b01 = *(const short8*)&fbp[1 * 256];   // ks0 s1
    short8 b10 = *(const short8*)&fbp[2 * 256];   // ks1 s0
    short8 b11 = *(const short8*)&fbp[3 * 256];   // ks1 s1
    float qv = (lo4 < 8) ? wsp[Q_OFF + lo4] : 0.f;
    f32x4 cc = {qv, qv, qv, qv};
    cc = MFMA_B16(a00, b00, cc, 0, 0, 0);
    cc = MFMA_B16(a10, b10, cc, 0, 0, 0);
    cc = MFMA_B16(a00, b01, cc, 0, 0, 0);
    cc = MFMA_B16(a01, b00, cc, 0, 0, 0);
    cc = MFMA_B16(a10, b11, cc, 0, 0, 0);
    cc = MFMA_B16(a11, b10, cc, 0, 0, 0);
    if (kg < 2 && lo4 < 8) {
#pragma unroll
      for (int reg = 0; reg < 4; ++reg)
        lds[C_OFF + (kg * 4 + reg) * 8 + lo4] = cc[reg];
    }
  }
  __syncthreads();   // barrier 1: V, c visible; hs staging drained

  // ---------- P2: scores + softmax (verified) ----------
  {
    const int p  = w;
    const int m_ = lane & 31;
    const int nn = lane >> 5;
    const int mm = (m_ < 20) ? m_ : 19;
    const bool act = (m_ < 20);
    const int mk = mm & 7;
    const float* hsb = &lds[HS_OFF + p * 1280 + mm * 64];
    const float* vb  = &lds[V_OFF + p * 520 + nn * 256];
    float s[4];
#pragma unroll
    for (int it = 0; it < 4; ++it) s[it] = lds[C_OFF + p * 8 + nn * 4 + it];
#pragma unroll
    for (int dq = 0; dq < 16; ++dq) {
      const int qs = dq ^ mk;
      const float4 h4 = *(const float4*)&hsb[qs * 4];
#pragma unroll
      for (int it = 0; it < 4; ++it) {
        const float4 v4 = *(const float4*)&vb[it * 64 + dq * 4];
        s[it] += h4.x * v4.x + h4.y * v4.y + h4.z * v4.z + h4.w * v4.w;
      }
    }
    const int lenp = (int)lds[LEN_OFF + p];
    float at[4];
#pragma unroll
    for (int it = 0; it < 4; ++it) {
      float sv = (act && m_ < lenp) ? s[it] : NEGV;
      float mx = sv;
#pragma unroll
      for (int o = 16; o; o >>= 1) mx = fmaxf(mx, __shfl_xor(mx, o, 32));
      const float e = act ? __expf(sv - mx) : 0.f;
      float sm = e;
#pragma unroll
      for (int o = 16; o; o >>= 1) sm += __shfl_xor(sm, o, 32);
      at[it] = e / sm;
    }
    if (act)
      *(float4*)&lds[ATT_OFF + p * 240 + m_ * 12 + nn * 4] =
          make_float4(at[0], at[1], at[2], at[3]);
  }
  // no barrier: P3 pair-local

  // ---------- P3: wv + fused 2-way split into this pair's V slice --------
  {
    const int p = w, d = lane;
    const int qd = d >> 2, r = d & 3;
    const float* hsb = &lds[HS_OFF + p * 1280];
    float wv[8] = {0.f, 0.f, 0.f, 0.f, 0.f, 0.f, 0.f, 0.f};
    const float* atp = &lds[ATT_OFF + p * 240];
#pragma unroll
    for (int m_ = 0; m_ < 20; ++m_) {
      const float h = hsb[m_ * 64 + ((qd ^ (m_ & 7)) << 2) + r];
      const float4 a0 = *(const float4*)&atp[m_ * 12];
      const float4 a1 = *(const float4*)&atp[m_ * 12 + 4];
      wv[0] += a0.x * h; wv[1] += a0.y * h; wv[2] += a0.z * h; wv[3] += a0.w * h;
      wv[4] += a1.x * h; wv[5] += a1.y * h; wv[6] += a1.z * h; wv[7] += a1.w * h;
    }
    ushort* wv2u = (ushort*)&lds[V_OFF];      // wv2 [p][2 s][520]u
#pragma unroll
    for (int n = 0; n < 8; ++n) {
      ushort h0, h1; split2(wv[n], h0, h1);
      wv2u[p * 1040 +       n * 64 + d] = h0;
      wv2u[p * 1040 + 520 + n * 64 + d] = h1;
    }
  }
  __syncthreads();   // barrier 2: all wv2 visible; hs arena dead

  // ---------- P4a (MFMA): wave (dt = w&3, ng = w>>2) ----------
  {
    const int dt = w & 3, ng = w >> 2;
    const ushort* wv2u = (const ushort*)&lds[V_OFF];
    f32x4 cc = {0.f, 0.f, 0.f, 0.f};
#pragma unroll
    for (int nn = 0; nn < 4; ++nn) {
      const int n = ng * 4 + nn;
      LOAD_A(wv2u, 1040, 520, rp8, n * 64 + kg * 8)
      const uint* fb = wsu + WFRAG + n * 4096 + lane * 4;
      SPLIT2_MFMA(fb, dt, cc)
    }
    if (kg < 2) {
#pragma unroll
      for (int reg = 0; reg < 4; ++reg)
        lds[HS_OFF + ng * 512 + (kg * 4 + reg) * 64 + dt * 16 + lo4] = cc[reg];
    }
  }
  __syncthreads();   // barrier 3

  // ---------- P4b: out = bf + y0 + y1 ----------
  {
    const int d = t & 63;
    out[(size_t)pair0 * 64 + t] =
        bf[d] + lds[HS_OFF + t] + lds[HS_OFF + 512 + t];
  }
}

extern "C" void kernel_launch(void* const* d_in, const int* in_sizes, int n_in,
                              void* d_out, int out_size, void* d_ws, size_t ws_size,
                              hipStream_t stream) {
  const float* ht  = (const float*)d_in[0];
  const float* hs  = (const float*)d_in[1];
  const int*   len = (const int*)d_in[2];
  const float* Wt  = (const float*)d_in[3];
  const float* bt  = (const float*)d_in[4];
  const float* Ws  = (const float*)d_in[5];
  const float* bs  = (const float*)d_in[6];
  const float* Wf  = (const float*)d_in[7];
  const float* bf  = (const float*)d_in[8];
  float* outp = (float*)d_out;
  float* ws   = (float*)d_ws;

  hipLaunchKernelGGL(prep_kernel, dim3(17), dim3(256), 0, stream,
                     Wt, bt, Ws, bs, Wf, ws);
  hipLaunchKernelGGL(attn_kernel, dim3(4096), dim3(512), 0, stream,
                     ht, hs, len, bf, ws, outp);
}

// Round 8
// 108.987 us; speedup vs baseline: 2.6676x; 1.0334x over previous
//
#include <hip/hip_runtime.h>
#include <hip/hip_bf16.h>

typedef __attribute__((ext_vector_type(8))) short short8;
typedef __attribute__((ext_vector_type(4))) float f32x4;

// dims: S=128, E=256 -> 32768 pairs; H=20, D=64, A=64, NH=8
constexpr float TEMP = 2.5f;    // H / sqrt(A) = 20/8
constexpr float NEGV = -1e9f;

// ---- workspace layout (dwords) ----
constexpr int K_OFF  = 0;       // k[8][64] f32 (TEMP-scaled)
constexpr int P_OFF  = 512;     // p[8][64] f32 (TEMP-scaled; source for PFRAG)
constexpr int Q_OFF  = 1024;    // q[8]     f32 (TEMP-scaled)
constexpr int PFRAG  = 1040;    // P  B-frags [2 ks][2 s][64 lane][4 dw] (1024)
constexpr int MFRAG  = 2064;    // M  B-frags [8 n][2 ks][4 dt][2 s][64][4] (32768)
constexpr int WFRAG  = 34832;   // Wf B-frags, same shape (32768)

// ---- main-kernel LDS layout (floats) ----
constexpr int HS_OFF  = 0;      // hs fp32 [8 p][20 m][16 quads] swizzled (10240)
                                //   after barrier 2: y[2 ng][8 p][64 d] @0
constexpr int HT_OFF  = 10240;  // ht fp32 [8][64]           (512)
constexpr int HT2_OFF = 10752;  // ht bf16 2-way [2][8][80]u (640)
constexpr int V_OFF   = 11392;  // V fp32 [8 p][n*72+d] (4608); after P2
                                //   (wave-local) wv2 bf16 [p][2 s][520]u
constexpr int ATT_OFF = 16000;  // attn[8][20][12] f32       (1920)
constexpr int C_OFF   = 17920;  // c[8 p][8 n]               (64)
constexpr int LEN_OFF = 17984;  // len[8]                    (8)
constexpr int LDS_FL  = 17992;  // 71,968 B -> 2 blocks/CU

#define MFMA_B16 __builtin_amdgcn_mfma_f32_16x16x32_bf16

// ---- bf16 split helpers ----
__device__ inline ushort bf16_rne(float x) {
  uint u = __float_as_uint(x);
  u += 0x7FFF + ((u >> 16) & 1);
  return (ushort)(u >> 16);
}
__device__ inline float bf16_f(ushort h) { return __uint_as_float(((uint)h) << 16); }
__device__ inline void split2(float x, ushort& h0, ushort& h1) {
  h0 = bf16_rne(x);
  h1 = bf16_rne(x - bf16_f(h0));
}
__device__ inline ushort split_lvl2(float x, int s) {
  ushort h0 = bf16_rne(x);
  return s == 0 ? h0 : bf16_rne(x - bf16_f(h0));
}
// packed 2-float split: u0 = bf16(x0)|bf16(x1)<<16 ; u1 = residual pair
__device__ inline void split2pk(float x0, float x1, uint& u0, uint& u1) {
  __hip_bfloat162 h = __float22bfloat162_rn(make_float2(x0, x1));
  uint u; __builtin_memcpy(&u, &h, 4);
  float r0 = x0 - __uint_as_float(u << 16);
  float r1 = x1 - __uint_as_float(u & 0xffff0000u);
  __hip_bfloat162 hr = __float22bfloat162_rn(make_float2(r0, r1));
  uint ur; __builtin_memcpy(&ur, &hr, 4);
  u0 = u; u1 = ur;
}
__device__ inline short8 pack4(uint a, uint b, uint c, uint d) {
  union { uint u[4]; short8 s; } cv;
  cv.u[0] = a; cv.u[1] = b; cv.u[2] = c; cv.u[3] = d;
  return cv.s;
}

// ============================================================
// prep (grid 17): 0..7 -> M[n] frags + k,p,q ; 8..15 -> Wf frags ;
//                 16 -> P frags.  (unchanged, verified R7)
// ============================================================
__global__ __launch_bounds__(256) void prep_kernel(
    const float* __restrict__ Wt, const float* __restrict__ bt,
    const float* __restrict__ Ws, const float* __restrict__ bs,
    const float* __restrict__ Wf, float* __restrict__ ws) {
  __shared__ float AL[64 * 65];
  __shared__ float BL[64 * 65];
  __shared__ float ML[64 * 65];
  const int t = threadIdx.x;
  uint* wsu = (uint*)ws;
  if (blockIdx.x < 8) {
    const int n = blockIdx.x;
#pragma unroll
    for (int i = 0; i < 16; ++i) {
      int idx = i * 256 + t;
      AL[(idx >> 6) * 65 + (idx & 63)] = Wt[n * 4096 + idx];
      BL[(idx >> 6) * 65 + (idx & 63)] = Ws[n * 4096 + idx];
    }
    __syncthreads();
#pragma unroll
    for (int i = 0; i < 16; ++i) {            // M[dp][d] = Wt[dp]·Ws[d] * TEMP
      int idx = i * 256 + t;
      int dp = idx >> 6, d = idx & 63;
      float acc = 0.f;
#pragma unroll 8
      for (int a = 0; a < 64; ++a) acc += AL[dp * 65 + a] * BL[d * 65 + a];
      ML[dp * 65 + d] = acc * TEMP;
    }
    if (t < 64) {
      float acc = 0.f;
#pragma unroll 8
      for (int a = 0; a < 64; ++a) acc += BL[t * 65 + a] * bt[n * 64 + a];
      ws[K_OFF + n * 64 + t] = acc * TEMP;
    } else if (t < 128) {
      int r = t - 64;
      float acc = 0.f;
#pragma unroll 8
      for (int a = 0; a < 64; ++a) acc += AL[r * 65 + a] * bs[n * 64 + a];
      ws[P_OFF + n * 64 + r] = acc * TEMP;
    } else if (t == 128) {
      float acc = 0.f;
      for (int a = 0; a < 64; ++a) acc += bt[n * 64 + a] * bs[n * 64 + a];
      ws[Q_OFF + n] = acc * TEMP;
    }
    __syncthreads();
#pragma unroll
    for (int i = 0; i < 16; ++i) {            // 4096 frag dwords (2-way split)
      int f = i * 256 + t;
      int r = f & 3, lane = (f >> 2) & 63, g = f >> 8;
      int s = g & 1, dt = (g >> 1) & 3, ks = g >> 3;
      int k = ks * 32 + ((lane >> 4) & 3) * 8 + r * 2;
      int d = dt * 16 + (lane & 15);
      uint lo = split_lvl2(ML[k * 65 + d], s);
      uint hi = split_lvl2(ML[(k + 1) * 65 + d], s);
      wsu[MFRAG + n * 4096 + (((ks * 4 + dt) * 2 + s) * 64 + lane) * 4 + r] =
          lo | (hi << 16);
    }
  } else if (blockIdx.x < 16) {
    const int n = blockIdx.x - 8;
#pragma unroll
    for (int i = 0; i < 16; ++i) {            // Wf rows n*64.. (k=dd, col=d)
      int idx = i * 256 + t;
      AL[(idx >> 6) * 65 + (idx & 63)] = Wf[(n * 64 + (idx >> 6)) * 64 + (idx & 63)];
    }
    __syncthreads();
#pragma unroll
    for (int i = 0; i < 16; ++i) {
      int f = i * 256 + t;
      int r = f & 3, lane = (f >> 2) & 63, g = f >> 8;
      int s = g & 1, dt = (g >> 1) & 3, ks = g >> 3;
      int k = ks * 32 + ((lane >> 4) & 3) * 8 + r * 2;
      int d = dt * 16 + (lane & 15);
      uint lo = split_lvl2(AL[k * 65 + d], s);
      uint hi = split_lvl2(AL[(k + 1) * 65 + d], s);
      wsu[WFRAG + n * 4096 + (((ks * 4 + dt) * 2 + s) * 64 + lane) * 4 + r] =
          lo | (hi << 16);
    }
  } else {
#pragma unroll
    for (int i = 0; i < 2; ++i) {
      int idx = i * 256 + t;                  // 0..511
      int n = idx >> 6, dp = idx & 63;
      float acc = 0.f;
#pragma unroll 8
      for (int a = 0; a < 64; ++a)
        acc += Wt[n * 4096 + dp * 64 + a] * bs[n * 64 + a];
      AL[idx] = acc * TEMP;                   // pL[n][dp]
    }
    __syncthreads();
#pragma unroll
    for (int i = 0; i < 4; ++i) {
      int f = i * 256 + t;
      int r = f & 3, lane = (f >> 2) & 63, g = f >> 8;
      int s = g & 1, ks = g >> 1;
      int k = ks * 32 + ((lane >> 4) & 3) * 8 + r * 2;
      int col = lane & 15;
      uint lo = (col < 8) ? (uint)split_lvl2(AL[col * 64 + k], s) : 0u;
      uint hi = (col < 8) ? (uint)split_lvl2(AL[col * 64 + k + 1], s) : 0u;
      wsu[PFRAG + ((ks * 2 + s) * 64 + lane) * 4 + r] = lo | (hi << 16);
    }
  }
}

// 2-way split-product cluster for global frags (verified R7)
#define SPLIT2_MFMA(FB, DT, CC)                                      \
  {                                                                  \
    short8 b00 = *(const short8*)&(FB)[((0 * 4 + (DT)) * 2 + 0) * 256]; \
    short8 b01 = *(const short8*)&(FB)[((0 * 4 + (DT)) * 2 + 1) * 256]; \
    short8 b10 = *(const short8*)&(FB)[((1 * 4 + (DT)) * 2 + 0) * 256]; \
    short8 b11 = *(const short8*)&(FB)[((1 * 4 + (DT)) * 2 + 1) * 256]; \
    CC = MFMA_B16(a00, b00, CC, 0, 0, 0);                            \
    CC = MFMA_B16(a10, b10, CC, 0, 0, 0);                            \
    CC = MFMA_B16(a00, b01, CC, 0, 0, 0);                            \
    CC = MFMA_B16(a01, b00, CC, 0, 0, 0);                            \
    CC = MFMA_B16(a10, b11, CC, 0, 0, 0);                            \
    CC = MFMA_B16(a11, b10, CC, 0, 0, 0);                            \
  }

#define LOAD_A(BASEU, ROWSTR, PLANESTR, ROW, KOFF)                   \
  short8 a00 = *(const short8*)&(BASEU)[(ROW) * (ROWSTR) + (KOFF)];               \
  short8 a01 = *(const short8*)&(BASEU)[(PLANESTR) + (ROW) * (ROWSTR) + (KOFF)];  \
  short8 a10 = *(const short8*)&(BASEU)[(ROW) * (ROWSTR) + 32 + (KOFF)];          \
  short8 a11 = *(const short8*)&(BASEU)[(PLANESTR) + (ROW) * (ROWSTR) + 32 + (KOFF)];

// ============================================================
// main: 8 pairs/block, 512 threads (8 waves), grid 4096.
// ============================================================
__global__ __launch_bounds__(512, 4) void attn_kernel(
    const float* __restrict__ ht_g, const float* __restrict__ hs_g,
    const int* __restrict__ len_g, const float* __restrict__ bf,
    const float* __restrict__ wsp, float* __restrict__ out) {
  __shared__ __align__(16) float lds[LDS_FL];
  const int t    = threadIdx.x;
  const int lane = t & 63;
  const int w    = t >> 6;
  const int pair0 = blockIdx.x * 8;
  ushort* ht2u = (ushort*)&lds[HT2_OFF];
  const uint* wsu = (const uint*)wsp;

  // ---------- stage ht + 2-way split + len ----------
  {
    float x = ht_g[(size_t)pair0 * 64 + t];
    lds[HT_OFF + t] = x;
    ushort h0, h1; split2(x, h0, h1);
    const int p = t >> 6, dp = t & 63;
    ht2u[0 * 640 + p * 80 + dp] = h0;
    ht2u[1 * 640 + p * 80 + dp] = h1;
  }
  if (t < 8) lds[LEN_OFF + t] = (float)len_g[pair0 + t];
  __syncthreads();   // barrier A: ht/ht2 visible

  // ---------- issue async hs staging (verified; drains at barrier 1) -----
  {
#pragma unroll
    for (int i = 0; i < 5; ++i) {
      const int c  = i * 512 + t;
      const int p  = c / 320;
      const int s  = c - p * 320;
      const int m  = s >> 4, qs = s & 15;
      const int q  = qs ^ (m & 7);
      const float* src = hs_g + (size_t)(pair0 + p) * 1280 + m * 64 + q * 4;
      __builtin_amdgcn_global_load_lds(
          (const __attribute__((address_space(1))) void*)src,
          (__attribute__((address_space(3))) void*)&lds[HS_OFF + (i * 512 + w * 64) * 4],
          16, 0, 0);
    }
  }

  const int lo4 = lane & 15, kg = lane >> 4;
  const int rp8 = lo4 & 7;

  // ---------- V phase (MFMA): wave = head n; V layout [p][n*72+d] --------
  {
    const int n = w;
    LOAD_A(ht2u, 80, 640, rp8, kg * 8)
    const uint* fb = wsu + MFRAG + n * 4096 + lane * 4;
    const float* kb = &wsp[K_OFF + n * 64 + lo4];
    float kv0 = kb[0], kv1 = kb[16], kv2 = kb[32], kv3 = kb[48];
    f32x4 c0 = {kv0, kv0, kv0, kv0};
    f32x4 c1 = {kv1, kv1, kv1, kv1};
    f32x4 c2 = {kv2, kv2, kv2, kv2};
    f32x4 c3 = {kv3, kv3, kv3, kv3};
    SPLIT2_MFMA(fb, 0, c0)
    SPLIT2_MFMA(fb, 1, c1)
    SPLIT2_MFMA(fb, 2, c2)
    SPLIT2_MFMA(fb, 3, c3)
    if (kg < 2) {
#pragma unroll
      for (int reg = 0; reg < 4; ++reg) {
        const int p = kg * 4 + reg;
        float* vp = &lds[V_OFF + p * 576 + n * 72 + lo4];
        vp[0]  = c0[reg];
        vp[16] = c1[reg];
        vp[32] = c2[reg];
        vp[48] = c3[reg];
      }
    }
  }

  // ---------- c (MFMA, wave 0): c[p][n] = q[n] + ht_p·p_n ----------
  if (w == 0) {
    LOAD_A(ht2u, 80, 640, rp8, kg * 8)
    const uint* fbp = wsu + PFRAG + lane * 4;
    short8 b00 = *(const short8*)&fbp[0 * 256];
    short8 b01 = *(const short8*)&fbp[1 * 256];
    short8 b10 = *(const short8*)&fbp[2 * 256];
    short8 b11 = *(const short8*)&fbp[3 * 256];
    float qv = (lo4 < 8) ? wsp[Q_OFF + lo4] : 0.f;
    f32x4 cc = {qv, qv, qv, qv};
    cc = MFMA_B16(a00, b00, cc, 0, 0, 0);
    cc = MFMA_B16(a10, b10, cc, 0, 0, 0);
    cc = MFMA_B16(a00, b01, cc, 0, 0, 0);
    cc = MFMA_B16(a01, b00, cc, 0, 0, 0);
    cc = MFMA_B16(a10, b11, cc, 0, 0, 0);
    cc = MFMA_B16(a11, b10, cc, 0, 0, 0);
    if (kg < 2 && lo4 < 8) {
#pragma unroll
      for (int reg = 0; reg < 4; ++reg)
        lds[C_OFF + (kg * 4 + reg) * 8 + lo4] = cc[reg];
    }
  }
  __syncthreads();   // barrier 1: V, c visible; hs staging drained

  // ---------- P2 (MFMA): scores + softmax. wave = pair ----------
  // scores[m][n] = c[p][n] + sum_d hs[m][d] * V[n][d]  (32x16x64, 2-way split)
  {
    const int p = w;
    const int n8 = rp8;
    const int lenp = (int)lds[LEN_OFF + p];
    // B-frags from V fp32 (consumer-side split)
    uint b00[4], b01[4], b10[4], b11[4];
    {
      const float* vb = &lds[V_OFF + p * 576 + n8 * 72 + kg * 8];
      float4 q0 = *(const float4*)&vb[0];
      float4 q1 = *(const float4*)&vb[4];
      split2pk(q0.x, q0.y, b00[0], b01[0]);
      split2pk(q0.z, q0.w, b00[1], b01[1]);
      split2pk(q1.x, q1.y, b00[2], b01[2]);
      split2pk(q1.z, q1.w, b00[3], b01[3]);
      q0 = *(const float4*)&vb[32];
      q1 = *(const float4*)&vb[36];
      split2pk(q0.x, q0.y, b10[0], b11[0]);
      split2pk(q0.z, q0.w, b10[1], b11[1]);
      split2pk(q1.x, q1.y, b10[2], b11[2]);
      split2pk(q1.z, q1.w, b10[3], b11[3]);
    }
    const short8 B00 = pack4(b00[0], b00[1], b00[2], b00[3]);
    const short8 B01 = pack4(b01[0], b01[1], b01[2], b01[3]);
    const short8 B10 = pack4(b10[0], b10[1], b10[2], b10[3]);
    const short8 B11 = pack4(b11[0], b11[1], b11[2], b11[3]);
    const float cv = lds[C_OFF + p * 8 + n8];
    f32x4 acc0 = {cv, cv, cv, cv};
    f32x4 acc1 = {cv, cv, cv, cv};
#pragma unroll
    for (int mt = 0; mt < 2; ++mt) {
      const int m = mt * 16 + lo4;
      const int m7 = m & 7;
      const float* hsb = &lds[HS_OFF + p * 1280 + m * 64];
      uint a0[4], a1[4], a2[4], a3[4];
      {
        const int qA = kg * 2;                // ks0 quads
        float4 q0 = *(const float4*)&hsb[(qA ^ m7) * 4];
        float4 q1 = *(const float4*)&hsb[((qA + 1) ^ m7) * 4];
        split2pk(q0.x, q0.y, a0[0], a1[0]);
        split2pk(q0.z, q0.w, a0[1], a1[1]);
        split2pk(q1.x, q1.y, a0[2], a1[2]);
        split2pk(q1.z, q1.w, a0[3], a1[3]);
        const int qB = 8 + kg * 2;            // ks1 quads
        q0 = *(const float4*)&hsb[(qB ^ m7) * 4];
        q1 = *(const float4*)&hsb[((qB + 1) ^ m7) * 4];
        split2pk(q0.x, q0.y, a2[0], a3[0]);
        split2pk(q0.z, q0.w, a2[1], a3[1]);
        split2pk(q1.x, q1.y, a2[2], a3[2]);
        split2pk(q1.z, q1.w, a2[3], a3[3]);
      }
      const short8 A00 = pack4(a0[0], a0[1], a0[2], a0[3]);
      const short8 A01 = pack4(a1[0], a1[1], a1[2], a1[3]);
      const short8 A10 = pack4(a2[0], a2[1], a2[2], a2[3]);
      const short8 A11 = pack4(a3[0], a3[1], a3[2], a3[3]);
      f32x4 acc = mt ? acc1 : acc0;
      acc = MFMA_B16(A00, B00, acc, 0, 0, 0);
      acc = MFMA_B16(A10, B10, acc, 0, 0, 0);
      acc = MFMA_B16(A00, B01, acc, 0, 0, 0);
      acc = MFMA_B16(A01, B00, acc, 0, 0, 0);
      acc = MFMA_B16(A10, B11, acc, 0, 0, 0);
      acc = MFMA_B16(A11, B10, acc, 0, 0, 0);
      if (mt) acc1 = acc; else acc0 = acc;
    }
    // softmax over m: regs (4+4) + cross-kg shfl; cols isolated (lo4 fixed)
    float e0[4], e1[4];
    float mx = NEGV;
#pragma unroll
    for (int r = 0; r < 4; ++r) {
      const int m0 = kg * 4 + r;
      const int m1 = 16 + kg * 4 + r;
      e0[r] = (m0 < lenp) ? acc0[r] : NEGV;
      e1[r] = (m1 < lenp) ? acc1[r] : NEGV;
      mx = fmaxf(mx, fmaxf(e0[r], e1[r]));
    }
    mx = fmaxf(mx, __shfl_xor(mx, 16));
    mx = fmaxf(mx, __shfl_xor(mx, 32));
    float sm = 0.f;
#pragma unroll
    for (int r = 0; r < 4; ++r) {
      e0[r] = __expf(e0[r] - mx);                       // masked -> exp(-1e9)=0
      e1[r] = (kg == 0) ? __expf(e1[r] - mx) : 0.f;     // pad rows m>=20 -> 0
      sm += e0[r] + e1[r];
    }
    sm += __shfl_xor(sm, 16);
    sm += __shfl_xor(sm, 32);
    const float inv = 1.0f / sm;
    if (lo4 < 8) {
#pragma unroll
      for (int r = 0; r < 4; ++r)
        lds[ATT_OFF + p * 240 + (kg * 4 + r) * 12 + lo4] = e0[r] * inv;
      if (kg == 0) {
#pragma unroll
        for (int r = 0; r < 4; ++r)
          lds[ATT_OFF + p * 240 + (16 + r) * 12 + lo4] = e1[r] * inv;
      }
    }
  }
  // no barrier: P3 pair-local (same wave wrote this pair's attn)

  // ---------- P3: wv + fused 2-way split into this pair's V slice --------
  {
    const int p = w, d = lane;
    const int qd = d >> 2, r = d & 3;
    const float* hsb = &lds[HS_OFF + p * 1280];
    float wv[8] = {0.f, 0.f, 0.f, 0.f, 0.f, 0.f, 0.f, 0.f};
    const float* atp = &lds[ATT_OFF + p * 240];
#pragma unroll
    for (int m_ = 0; m_ < 20; ++m_) {
      const float h = hsb[m_ * 64 + ((qd ^ (m_ & 7)) << 2) + r];
      const float4 a0 = *(const float4*)&atp[m_ * 12];
      const float4 a1 = *(const float4*)&atp[m_ * 12 + 4];
      wv[0] += a0.x * h; wv[1] += a0.y * h; wv[2] += a0.z * h; wv[3] += a0.w * h;
      wv[4] += a1.x * h; wv[5] += a1.y * h; wv[6] += a1.z * h; wv[7] += a1.w * h;
    }
    ushort* wv2u = (ushort*)&lds[V_OFF];      // wv2 [p][2 s][520]u in [p][1152]u
#pragma unroll
    for (int n = 0; n < 8; ++n) {
      ushort h0, h1; split2(wv[n], h0, h1);
      wv2u[p * 1152 +       n * 64 + d] = h0;
      wv2u[p * 1152 + 520 + n * 64 + d] = h1;
    }
  }
  __syncthreads();   // barrier 2: all wv2 visible; hs arena dead

  // ---------- P4a (MFMA): wave (dt = w&3, ng = w>>2) ----------
  {
    const int dt = w & 3, ng = w >> 2;
    const ushort* wv2u = (const ushort*)&lds[V_OFF];
    f32x4 cc = {0.f, 0.f, 0.f, 0.f};
#pragma unroll
    for (int nn = 0; nn < 4; ++nn) {
      const int n = ng * 4 + nn;
      LOAD_A(wv2u, 1152, 520, rp8, n * 64 + kg * 8)
      const uint* fb = wsu + WFRAG + n * 4096 + lane * 4;
      SPLIT2_MFMA(fb, dt, cc)
    }
    if (kg < 2) {
#pragma unroll
      for (int reg = 0; reg < 4; ++reg)
        lds[HS_OFF + ng * 512 + (kg * 4 + reg) * 64 + dt * 16 + lo4] = cc[reg];
    }
  }
  __syncthreads();   // barrier 3

  // ---------- P4b: out = bf + y0 + y1 ----------
  {
    const int d = t & 63;
    out[(size_t)pair0 * 64 + t] =
        bf[d] + lds[HS_OFF + t] + lds[HS_OFF + 512 + t];
  }
}

extern "C" void kernel_launch(void* const* d_in, const int* in_sizes, int n_in,
                              void* d_out, int out_size, void* d_ws, size_t ws_size,
                              hipStream_t stream) {
  const float* ht  = (const float*)d_in[0];
  const float* hs  = (const float*)d_in[1];
  const int*   len = (const int*)d_in[2];
  const float* Wt  = (const float*)d_in[3];
  const float* bt  = (const float*)d_in[4];
  const float* Ws  = (const float*)d_in[5];
  const float* bs  = (const float*)d_in[6];
  const float* Wf  = (const float*)d_in[7];
  const float* bf  = (const float*)d_in[8];
  float* outp = (float*)d_out;
  float* ws   = (float*)d_ws;

  hipLaunchKernelGGL(prep_kernel, dim3(17), dim3(256), 0, stream,
                     Wt, bt, Ws, bs, Wf, ws);
  hipLaunchKernelGGL(attn_kernel, dim3(4096), dim3(512), 0, stream,
                     ht, hs, len, bf, ws, outp);
}

// Round 9
// 102.191 us; speedup vs baseline: 2.8450x; 1.0665x over previous
//
#include <hip/hip_runtime.h>
#include <hip/hip_bf16.h>

typedef __attribute__((ext_vector_type(8))) short short8;
typedef __attribute__((ext_vector_type(4))) float f32x4;

// dims: S=128, E=256 -> 32768 pairs; H=20, D=64, A=64, NH=8
constexpr float TEMP = 2.5f;    // H / sqrt(A) = 20/8
constexpr float NEGV = -1e9f;

// ---- workspace layout (dwords) ----
constexpr int K_OFF  = 0;       // k[8][64] f32 (TEMP-scaled)
constexpr int P_OFF  = 512;     // p[8][64] f32 (TEMP-scaled; source for PFRAG)
constexpr int Q_OFF  = 1024;    // q[8]     f32 (TEMP-scaled)
constexpr int PFRAG  = 1040;    // P  B-frags [2 ks][2 s][64 lane][4 dw] (1024)
constexpr int MFRAG  = 2064;    // M  B-frags [8 n][2 ks][4 dt][2 s][64][4] (32768)
constexpr int WFRAG  = 34832;   // Wf B-frags, same shape (32768)

// ---- main-kernel LDS layout (floats) ----
constexpr int HS_OFF  = 0;      // hs fp32 [8 p][20 m][16 quads] swizzled (10240)
                                //   after barrier 2: y[2 ng][8 p][64 d] @0
constexpr int HT_OFF  = 10240;  // ht fp32 [8][64]           (512)
constexpr int HT2_OFF = 10752;  // ht bf16 2-way [2][8][80]u (640)
constexpr int V_OFF   = 11392;  // V fp32 [8 p][n*76+d] (608/pair, 4864 total)
                                //   bank math: n*76+kg*8 mod 32 covers all 8
                                //   multiples of 4 -> conflict-free b128 reads.
                                //   after P2 (wave-local): wv2 bf16
                                //   [p][2 s][520]u, pair stride 1096 u
                                //   (rp8*548 mod 32 = rp8*4 -> 8 distinct starts)
constexpr int ATT_OFF = 16256;  // attn[8][20][12] f32       (1920)
constexpr int C_OFF   = 18176;  // c[8 p][8 n]               (64)
constexpr int LEN_OFF = 18240;  // len[8]                    (8)
constexpr int LDS_FL  = 18248;  // 72,992 B -> 2 blocks/CU

#define MFMA_B16 __builtin_amdgcn_mfma_f32_16x16x32_bf16

// ---- bf16 split helpers ----
__device__ inline ushort bf16_rne(float x) {
  uint u = __float_as_uint(x);
  u += 0x7FFF + ((u >> 16) & 1);
  return (ushort)(u >> 16);
}
__device__ inline float bf16_f(ushort h) { return __uint_as_float(((uint)h) << 16); }
__device__ inline void split2(float x, ushort& h0, ushort& h1) {
  h0 = bf16_rne(x);
  h1 = bf16_rne(x - bf16_f(h0));
}
__device__ inline ushort split_lvl2(float x, int s) {
  ushort h0 = bf16_rne(x);
  return s == 0 ? h0 : bf16_rne(x - bf16_f(h0));
}
// packed 2-float split: u0 = bf16(x0)|bf16(x1)<<16 ; u1 = residual pair
__device__ inline void split2pk(float x0, float x1, uint& u0, uint& u1) {
  __hip_bfloat162 h = __float22bfloat162_rn(make_float2(x0, x1));
  uint u; __builtin_memcpy(&u, &h, 4);
  float r0 = x0 - __uint_as_float(u << 16);
  float r1 = x1 - __uint_as_float(u & 0xffff0000u);
  __hip_bfloat162 hr = __float22bfloat162_rn(make_float2(r0, r1));
  uint ur; __builtin_memcpy(&ur, &hr, 4);
  u0 = u; u1 = ur;
}
__device__ inline short8 pack4(uint a, uint b, uint c, uint d) {
  union { uint u[4]; short8 s; } cv;
  cv.u[0] = a; cv.u[1] = b; cv.u[2] = c; cv.u[3] = d;
  return cv.s;
}

// ============================================================
// prep (grid 17): 0..7 -> M[n] frags + k,p,q ; 8..15 -> Wf frags ;
//                 16 -> P frags.  (unchanged, verified R7/R8)
// ============================================================
__global__ __launch_bounds__(256) void prep_kernel(
    const float* __restrict__ Wt, const float* __restrict__ bt,
    const float* __restrict__ Ws, const float* __restrict__ bs,
    const float* __restrict__ Wf, float* __restrict__ ws) {
  __shared__ float AL[64 * 65];
  __shared__ float BL[64 * 65];
  __shared__ float ML[64 * 65];
  const int t = threadIdx.x;
  uint* wsu = (uint*)ws;
  if (blockIdx.x < 8) {
    const int n = blockIdx.x;
#pragma unroll
    for (int i = 0; i < 16; ++i) {
      int idx = i * 256 + t;
      AL[(idx >> 6) * 65 + (idx & 63)] = Wt[n * 4096 + idx];
      BL[(idx >> 6) * 65 + (idx & 63)] = Ws[n * 4096 + idx];
    }
    __syncthreads();
#pragma unroll
    for (int i = 0; i < 16; ++i) {            // M[dp][d] = Wt[dp]·Ws[d] * TEMP
      int idx = i * 256 + t;
      int dp = idx >> 6, d = idx & 63;
      float acc = 0.f;
#pragma unroll 8
      for (int a = 0; a < 64; ++a) acc += AL[dp * 65 + a] * BL[d * 65 + a];
      ML[dp * 65 + d] = acc * TEMP;
    }
    if (t < 64) {
      float acc = 0.f;
#pragma unroll 8
      for (int a = 0; a < 64; ++a) acc += BL[t * 65 + a] * bt[n * 64 + a];
      ws[K_OFF + n * 64 + t] = acc * TEMP;
    } else if (t < 128) {
      int r = t - 64;
      float acc = 0.f;
#pragma unroll 8
      for (int a = 0; a < 64; ++a) acc += AL[r * 65 + a] * bs[n * 64 + a];
      ws[P_OFF + n * 64 + r] = acc * TEMP;
    } else if (t == 128) {
      float acc = 0.f;
      for (int a = 0; a < 64; ++a) acc += bt[n * 64 + a] * bs[n * 64 + a];
      ws[Q_OFF + n] = acc * TEMP;
    }
    __syncthreads();
#pragma unroll
    for (int i = 0; i < 16; ++i) {            // 4096 frag dwords (2-way split)
      int f = i * 256 + t;
      int r = f & 3, lane = (f >> 2) & 63, g = f >> 8;
      int s = g & 1, dt = (g >> 1) & 3, ks = g >> 3;
      int k = ks * 32 + ((lane >> 4) & 3) * 8 + r * 2;
      int d = dt * 16 + (lane & 15);
      uint lo = split_lvl2(ML[k * 65 + d], s);
      uint hi = split_lvl2(ML[(k + 1) * 65 + d], s);
      wsu[MFRAG + n * 4096 + (((ks * 4 + dt) * 2 + s) * 64 + lane) * 4 + r] =
          lo | (hi << 16);
    }
  } else if (blockIdx.x < 16) {
    const int n = blockIdx.x - 8;
#pragma unroll
    for (int i = 0; i < 16; ++i) {            // Wf rows n*64.. (k=dd, col=d)
      int idx = i * 256 + t;
      AL[(idx >> 6) * 65 + (idx & 63)] = Wf[(n * 64 + (idx >> 6)) * 64 + (idx & 63)];
    }
    __syncthreads();
#pragma unroll
    for (int i = 0; i < 16; ++i) {
      int f = i * 256 + t;
      int r = f & 3, lane = (f >> 2) & 63, g = f >> 8;
      int s = g & 1, dt = (g >> 1) & 3, ks = g >> 3;
      int k = ks * 32 + ((lane >> 4) & 3) * 8 + r * 2;
      int d = dt * 16 + (lane & 15);
      uint lo = split_lvl2(AL[k * 65 + d], s);
      uint hi = split_lvl2(AL[(k + 1) * 65 + d], s);
      wsu[WFRAG + n * 4096 + (((ks * 4 + dt) * 2 + s) * 64 + lane) * 4 + r] =
          lo | (hi << 16);
    }
  } else {
#pragma unroll
    for (int i = 0; i < 2; ++i) {
      int idx = i * 256 + t;                  // 0..511
      int n = idx >> 6, dp = idx & 63;
      float acc = 0.f;
#pragma unroll 8
      for (int a = 0; a < 64; ++a)
        acc += Wt[n * 4096 + dp * 64 + a] * bs[n * 64 + a];
      AL[idx] = acc * TEMP;                   // pL[n][dp]
    }
    __syncthreads();
#pragma unroll
    for (int i = 0; i < 4; ++i) {
      int f = i * 256 + t;
      int r = f & 3, lane = (f >> 2) & 63, g = f >> 8;
      int s = g & 1, ks = g >> 1;
      int k = ks * 32 + ((lane >> 4) & 3) * 8 + r * 2;
      int col = lane & 15;
      uint lo = (col < 8) ? (uint)split_lvl2(AL[col * 64 + k], s) : 0u;
      uint hi = (col < 8) ? (uint)split_lvl2(AL[col * 64 + k + 1], s) : 0u;
      wsu[PFRAG + ((ks * 2 + s) * 64 + lane) * 4 + r] = lo | (hi << 16);
    }
  }
}

// 2-way split-product cluster for global frags (verified R7)
#define SPLIT2_MFMA(FB, DT, CC)                                      \
  {                                                                  \
    short8 b00 = *(const short8*)&(FB)[((0 * 4 + (DT)) * 2 + 0) * 256]; \
    short8 b01 = *(const short8*)&(FB)[((0 * 4 + (DT)) * 2 + 1) * 256]; \
    short8 b10 = *(const short8*)&(FB)[((1 * 4 + (DT)) * 2 + 0) * 256]; \
    short8 b11 = *(const short8*)&(FB)[((1 * 4 + (DT)) * 2 + 1) * 256]; \
    CC = MFMA_B16(a00, b00, CC, 0, 0, 0);                            \
    CC = MFMA_B16(a10, b10, CC, 0, 0, 0);                            \
    CC = MFMA_B16(a00, b01, CC, 0, 0, 0);                            \
    CC = MFMA_B16(a01, b00, CC, 0, 0, 0);                            \
    CC = MFMA_B16(a10, b11, CC, 0, 0, 0);                            \
    CC = MFMA_B16(a11, b10, CC, 0, 0, 0);                            \
  }

#define LOAD_A(BASEU, ROWSTR, PLANESTR, ROW, KOFF)                   \
  short8 a00 = *(const short8*)&(BASEU)[(ROW) * (ROWSTR) + (KOFF)];               \
  short8 a01 = *(const short8*)&(BASEU)[(PLANESTR) + (ROW) * (ROWSTR) + (KOFF)];  \
  short8 a10 = *(const short8*)&(BASEU)[(ROW) * (ROWSTR) + 32 + (KOFF)];          \
  short8 a11 = *(const short8*)&(BASEU)[(PLANESTR) + (ROW) * (ROWSTR) + 32 + (KOFF)];

// ============================================================
// main: 8 pairs/block, 512 threads (8 waves), grid 4096.
// ============================================================
__global__ __launch_bounds__(512, 4) void attn_kernel(
    const float* __restrict__ ht_g, const float* __restrict__ hs_g,
    const int* __restrict__ len_g, const float* __restrict__ bf,
    const float* __restrict__ wsp, float* __restrict__ out) {
  __shared__ __align__(16) float lds[LDS_FL];
  const int t    = threadIdx.x;
  const int lane = t & 63;
  const int w    = t >> 6;
  const int pair0 = blockIdx.x * 8;
  ushort* ht2u = (ushort*)&lds[HT2_OFF];
  const uint* wsu = (const uint*)wsp;

  // ---------- stage ht + 2-way split + len ----------
  {
    float x = ht_g[(size_t)pair0 * 64 + t];
    lds[HT_OFF + t] = x;
    ushort h0, h1; split2(x, h0, h1);
    const int p = t >> 6, dp = t & 63;
    ht2u[0 * 640 + p * 80 + dp] = h0;
    ht2u[1 * 640 + p * 80 + dp] = h1;
  }
  if (t < 8) lds[LEN_OFF + t] = (float)len_g[pair0 + t];
  __syncthreads();   // barrier A: ht/ht2 visible

  // ---------- issue async hs staging (verified; drains at barrier 1) -----
  {
#pragma unroll
    for (int i = 0; i < 5; ++i) {
      const int c  = i * 512 + t;
      const int p  = c / 320;
      const int s  = c - p * 320;
      const int m  = s >> 4, qs = s & 15;
      const int q  = qs ^ (m & 7);
      const float* src = hs_g + (size_t)(pair0 + p) * 1280 + m * 64 + q * 4;
      __builtin_amdgcn_global_load_lds(
          (const __attribute__((address_space(1))) void*)src,
          (__attribute__((address_space(3))) void*)&lds[HS_OFF + (i * 512 + w * 64) * 4],
          16, 0, 0);
    }
  }

  const int lo4 = lane & 15, kg = lane >> 4;
  const int rp8 = lo4 & 7;

  // ---------- V phase (MFMA): wave = head n; V layout [p][n*76+d] --------
  {
    const int n = w;
    LOAD_A(ht2u, 80, 640, rp8, kg * 8)
    const uint* fb = wsu + MFRAG + n * 4096 + lane * 4;
    const float* kb = &wsp[K_OFF + n * 64 + lo4];
    float kv0 = kb[0], kv1 = kb[16], kv2 = kb[32], kv3 = kb[48];
    f32x4 c0 = {kv0, kv0, kv0, kv0};
    f32x4 c1 = {kv1, kv1, kv1, kv1};
    f32x4 c2 = {kv2, kv2, kv2, kv2};
    f32x4 c3 = {kv3, kv3, kv3, kv3};
    SPLIT2_MFMA(fb, 0, c0)
    SPLIT2_MFMA(fb, 1, c1)
    SPLIT2_MFMA(fb, 2, c2)
    SPLIT2_MFMA(fb, 3, c3)
    if (kg < 2) {
#pragma unroll
      for (int reg = 0; reg < 4; ++reg) {
        const int p = kg * 4 + reg;
        float* vp = &lds[V_OFF + p * 608 + n * 76 + lo4];
        vp[0]  = c0[reg];
        vp[16] = c1[reg];
        vp[32] = c2[reg];
        vp[48] = c3[reg];
      }
    }
  }

  // ---------- c (MFMA, wave 0): c[p][n] = q[n] + ht_p·p_n ----------
  if (w == 0) {
    LOAD_A(ht2u, 80, 640, rp8, kg * 8)
    const uint* fbp = wsu + PFRAG + lane * 4;
    short8 b00 = *(const short8*)&fbp[0 * 256];
    short8 b01 = *(const short8*)&fbp[1 * 256];
    short8 b10 = *(const short8*)&fbp[2 * 256];
    short8 b11 = *(const short8*)&fbp[3 * 256];
    float qv = (lo4 < 8) ? wsp[Q_OFF + lo4] : 0.f;
    f32x4 cc = {qv, qv, qv, qv};
    cc = MFMA_B16(a00, b00, cc, 0, 0, 0);
    cc = MFMA_B16(a10, b10, cc, 0, 0, 0);
    cc = MFMA_B16(a00, b01, cc, 0, 0, 0);
    cc = MFMA_B16(a01, b00, cc, 0, 0, 0);
    cc = MFMA_B16(a10, b11, cc, 0, 0, 0);
    cc = MFMA_B16(a11, b10, cc, 0, 0, 0);
    if (kg < 2 && lo4 < 8) {
#pragma unroll
      for (int reg = 0; reg < 4; ++reg)
        lds[C_OFF + (kg * 4 + reg) * 8 + lo4] = cc[reg];
    }
  }
  __syncthreads();   // barrier 1: V, c visible; hs staging drained

  // ---------- P2 (MFMA): scores + softmax. wave = pair ----------
  // scores[m][n] = c[p][n] + sum_d hs[m][d] * V[n][d]  (32x16x64, 2-way split)
  {
    const int p = w;
    const int n8 = rp8;
    const int lenp = (int)lds[LEN_OFF + p];
    // B-frags from V fp32 (consumer-side split)
    uint b00[4], b01[4], b10[4], b11[4];
    {
      const float* vb = &lds[V_OFF + p * 608 + n8 * 76 + kg * 8];
      float4 q0 = *(const float4*)&vb[0];
      float4 q1 = *(const float4*)&vb[4];
      split2pk(q0.x, q0.y, b00[0], b01[0]);
      split2pk(q0.z, q0.w, b00[1], b01[1]);
      split2pk(q1.x, q1.y, b00[2], b01[2]);
      split2pk(q1.z, q1.w, b00[3], b01[3]);
      q0 = *(const float4*)&vb[32];
      q1 = *(const float4*)&vb[36];
      split2pk(q0.x, q0.y, b10[0], b11[0]);
      split2pk(q0.z, q0.w, b10[1], b11[1]);
      split2pk(q1.x, q1.y, b10[2], b11[2]);
      split2pk(q1.z, q1.w, b10[3], b11[3]);
    }
    const short8 B00 = pack4(b00[0], b00[1], b00[2], b00[3]);
    const short8 B01 = pack4(b01[0], b01[1], b01[2], b01[3]);
    const short8 B10 = pack4(b10[0], b10[1], b10[2], b10[3]);
    const short8 B11 = pack4(b11[0], b11[1], b11[2], b11[3]);
    const float cv = lds[C_OFF + p * 8 + n8];
    f32x4 acc0 = {cv, cv, cv, cv};
    f32x4 acc1 = {cv, cv, cv, cv};
#pragma unroll
    for (int mt = 0; mt < 2; ++mt) {
      const int m = mt * 16 + lo4;
      const int m7 = m & 7;
      const float* hsb = &lds[HS_OFF + p * 1280 + m * 64];
      uint a0[4], a1[4], a2[4], a3[4];
      {
        const int qA = kg * 2;                // ks0 quads
        float4 q0 = *(const float4*)&hsb[(qA ^ m7) * 4];
        float4 q1 = *(const float4*)&hsb[((qA + 1) ^ m7) * 4];
        split2pk(q0.x, q0.y, a0[0], a1[0]);
        split2pk(q0.z, q0.w, a0[1], a1[1]);
        split2pk(q1.x, q1.y, a0[2], a1[2]);
        split2pk(q1.z, q1.w, a0[3], a1[3]);
        const int qB = 8 + kg * 2;            // ks1 quads
        q0 = *(const float4*)&hsb[(qB ^ m7) * 4];
        q1 = *(const float4*)&hsb[((qB + 1) ^ m7) * 4];
        split2pk(q0.x, q0.y, a2[0], a3[0]);
        split2pk(q0.z, q0.w, a2[1], a3[1]);
        split2pk(q1.x, q1.y, a2[2], a3[2]);
        split2pk(q1.z, q1.w, a2[3], a3[3]);
      }
      const short8 A00 = pack4(a0[0], a0[1], a0[2], a0[3]);
      const short8 A01 = pack4(a1[0], a1[1], a1[2], a1[3]);
      const short8 A10 = pack4(a2[0], a2[1], a2[2], a2[3]);
      const short8 A11 = pack4(a3[0], a3[1], a3[2], a3[3]);
      f32x4 acc = mt ? acc1 : acc0;
      acc = MFMA_B16(A00, B00, acc, 0, 0, 0);
      acc = MFMA_B16(A10, B10, acc, 0, 0, 0);
      acc = MFMA_B16(A00, B01, acc, 0, 0, 0);
      acc = MFMA_B16(A01, B00, acc, 0, 0, 0);
      acc = MFMA_B16(A10, B11, acc, 0, 0, 0);
      acc = MFMA_B16(A11, B10, acc, 0, 0, 0);
      if (mt) acc1 = acc; else acc0 = acc;
    }
    // softmax over m: regs (4+4) + cross-kg shfl; cols isolated (lo4 fixed)
    float e0[4], e1[4];
    float mx = NEGV;
#pragma unroll
    for (int r = 0; r < 4; ++r) {
      const int m0 = kg * 4 + r;
      const int m1 = 16 + kg * 4 + r;
      e0[r] = (m0 < lenp) ? acc0[r] : NEGV;
      e1[r] = (m1 < lenp) ? acc1[r] : NEGV;
      mx = fmaxf(mx, fmaxf(e0[r], e1[r]));
    }
    mx = fmaxf(mx, __shfl_xor(mx, 16));
    mx = fmaxf(mx, __shfl_xor(mx, 32));
    float sm = 0.f;
#pragma unroll
    for (int r = 0; r < 4; ++r) {
      e0[r] = __expf(e0[r] - mx);                       // masked -> exp(-1e9)=0
      e1[r] = (kg == 0) ? __expf(e1[r] - mx) : 0.f;     // pad rows m>=20 -> 0
      sm += e0[r] + e1[r];
    }
    sm += __shfl_xor(sm, 16);
    sm += __shfl_xor(sm, 32);
    const float inv = 1.0f / sm;
    if (lo4 < 8) {
#pragma unroll
      for (int r = 0; r < 4; ++r)
        lds[ATT_OFF + p * 240 + (kg * 4 + r) * 12 + lo4] = e0[r] * inv;
      if (kg == 0) {
#pragma unroll
        for (int r = 0; r < 4; ++r)
          lds[ATT_OFF + p * 240 + (16 + r) * 12 + lo4] = e1[r] * inv;
      }
    }
  }
  // no barrier: P3 pair-local (same wave wrote this pair's attn)

  // ---------- P3: wv + fused 2-way split into this pair's V slice --------
  {
    const int p = w, d = lane;
    const int qd = d >> 2, r = d & 3;
    const float* hsb = &lds[HS_OFF + p * 1280];
    float wv[8] = {0.f, 0.f, 0.f, 0.f, 0.f, 0.f, 0.f, 0.f};
    const float* atp = &lds[ATT_OFF + p * 240];
#pragma unroll
    for (int m_ = 0; m_ < 20; ++m_) {
      const float h = hsb[m_ * 64 + ((qd ^ (m_ & 7)) << 2) + r];
      const float4 a0 = *(const float4*)&atp[m_ * 12];
      const float4 a1 = *(const float4*)&atp[m_ * 12 + 4];
      wv[0] += a0.x * h; wv[1] += a0.y * h; wv[2] += a0.z * h; wv[3] += a0.w * h;
      wv[4] += a1.x * h; wv[5] += a1.y * h; wv[6] += a1.z * h; wv[7] += a1.w * h;
    }
    ushort* wv2u = (ushort*)&lds[V_OFF];      // wv2 [p][2 s][520]u, stride 1096u
#pragma unroll
    for (int n = 0; n < 8; ++n) {
      ushort h0, h1; split2(wv[n], h0, h1);
      wv2u[p * 1096 +       n * 64 + d] = h0;
      wv2u[p * 1096 + 520 + n * 64 + d] = h1;
    }
  }
  __syncthreads();   // barrier 2: all wv2 visible; hs arena dead

  // ---------- P4a (MFMA): wave (dt = w&3, ng = w>>2) ----------
  {
    const int dt = w & 3, ng = w >> 2;
    const ushort* wv2u = (const ushort*)&lds[V_OFF];
    f32x4 cc = {0.f, 0.f, 0.f, 0.f};
#pragma unroll
    for (int nn = 0; nn < 4; ++nn) {
      const int n = ng * 4 + nn;
      LOAD_A(wv2u, 1096, 520, rp8, n * 64 + kg * 8)
      const uint* fb = wsu + WFRAG + n * 4096 + lane * 4;
      SPLIT2_MFMA(fb, dt, cc)
    }
    if (kg < 2) {
#pragma unroll
      for (int reg = 0; reg < 4; ++reg)
        lds[HS_OFF + ng * 512 + (kg * 4 + reg) * 64 + dt * 16 + lo4] = cc[reg];
    }
  }
  __syncthreads();   // barrier 3

  // ---------- P4b: out = bf + y0 + y1 ----------
  {
    const int d = t & 63;
    out[(size_t)pair0 * 64 + t] =
        bf[d] + lds[HS_OFF + t] + lds[HS_OFF + 512 + t];
  }
}

extern "C" void kernel_launch(void* const* d_in, const int* in_sizes, int n_in,
                              void* d_out, int out_size, void* d_ws, size_t ws_size,
                              hipStream_t stream) {
  const float* ht  = (const float*)d_in[0];
  const float* hs  = (const float*)d_in[1];
  const int*   len = (const int*)d_in[2];
  const float* Wt  = (const float*)d_in[3];
  const float* bt  = (const float*)d_in[4];
  const float* Ws  = (const float*)d_in[5];
  const float* bs  = (const float*)d_in[6];
  const float* Wf  = (const float*)d_in[7];
  const float* bf  = (const float*)d_in[8];
  float* outp = (float*)d_out;
  float* ws   = (float*)d_ws;

  hipLaunchKernelGGL(prep_kernel, dim3(17), dim3(256), 0, stream,
                     Wt, bt, Ws, bs, Wf, ws);
  hipLaunchKernelGGL(attn_kernel, dim3(4096), dim3(512), 0, stream,
                     ht, hs, len, bf, ws, outp);
}

// Round 11
// 94.502 us; speedup vs baseline: 3.0764x; 1.0814x over previous
//
#include <hip/hip_runtime.h>
#include <hip/hip_bf16.h>

typedef __attribute__((ext_vector_type(8))) short short8;
typedef __attribute__((ext_vector_type(4))) float f32x4;

// dims: S=128, E=256 -> 32768 pairs; H=20, D=64, A=64, NH=8
constexpr float TEMP = 2.5f;    // H / sqrt(A) = 20/8
constexpr float NEGV = -1e9f;

// ---- workspace layout (dwords) ----
constexpr int K_OFF  = 0;       // k[8][64] f32 (TEMP-scaled)
constexpr int P_OFF  = 512;     // p[8][64] f32 (TEMP-scaled; source for PFRAG)
constexpr int Q_OFF  = 1024;    // q[8]     f32 (TEMP-scaled)
constexpr int PFRAG  = 1040;    // P  B-frags [2 ks][2 s][64 lane][4 dw] (1024)
constexpr int MFRAG  = 2064;    // M  B-frags [8 n][2 ks][4 dt][2 s][64][4] (32768)
constexpr int WFRAG  = 34832;   // Wf B-frags, same shape (32768)

// ---- main-kernel LDS layout ----
// u16 units:
constexpr int HS2_U   = 0;      // hs bf16 2-plane [2 s][8 p][20 m][72]
constexpr int HS2_PL  = 11520;  //   plane stride; pair 1440; row 72
                                //   (23040 u16; after barrier 2: y f32 @0)
constexpr int V2_U    = 23040;  // V bf16 2-plane [2 s][8 p][n*72+d]
constexpr int V2_PL   = 4672;   //   plane stride; pair 584 (8*72+8 pad)
                                //   (9344 u16; after P2: wv, same layout)
constexpr int HT2_U   = 32384;  // ht bf16 2-way [2 s][8 p][80] (1280 u16)
// f32 units (u16 total 33664 -> f32 offset 16832):
constexpr int ATT_F = 16832;    // attn[8][20][12] f32       (1920)
constexpr int C_F   = 18752;    // c[8 p][8 n]               (64)
constexpr int LEN_F = 18816;    // len[8]                    (8)
constexpr int LDS_FL = 18824;   // 75,296 B -> 2 blocks/CU

#define MFMA_B16 __builtin_amdgcn_mfma_f32_16x16x32_bf16

// ---- bf16 helpers ----
__device__ inline ushort bf16_rne(float x) {
  uint u = __float_as_uint(x);
  u += 0x7FFF + ((u >> 16) & 1);
  return (ushort)(u >> 16);
}
__device__ inline float bf16_f(ushort h) { return __uint_as_float(((uint)h) << 16); }
__device__ inline void split2(float x, ushort& h0, ushort& h1) {
  h0 = bf16_rne(x);
  h1 = bf16_rne(x - bf16_f(h0));
}
__device__ inline ushort split_lvl2(float x, int s) {
  ushort h0 = bf16_rne(x);
  return s == 0 ? h0 : bf16_rne(x - bf16_f(h0));
}
__device__ inline uint2 pkbf16x4(float4 v) {
  __hip_bfloat162 h0 = __float22bfloat162_rn(make_float2(v.x, v.y));
  __hip_bfloat162 h1 = __float22bfloat162_rn(make_float2(v.z, v.w));
  uint2 r; __builtin_memcpy(&r.x, &h0, 4); __builtin_memcpy(&r.y, &h1, 4);
  return r;
}
// 4-float 2-plane split: u0 = bf16 pair-packed, u1 = packed residuals
__device__ inline void pksplit4(float4 v, uint2& u0, uint2& u1) {
  u0 = pkbf16x4(v);
  float4 r;
  r.x = v.x - __uint_as_float(u0.x << 16);
  r.y = v.y - __uint_as_float(u0.x & 0xffff0000u);
  r.z = v.z - __uint_as_float(u0.y << 16);
  r.w = v.w - __uint_as_float(u0.y & 0xffff0000u);
  u1 = pkbf16x4(r);
}

// ============================================================
// prep (grid 17): 0..7 -> M[n] frags + k,p,q ; 8..15 -> Wf frags ;
//                 16 -> P frags.  (unchanged, verified R7-R9)
// ============================================================
__global__ __launch_bounds__(256) void prep_kernel(
    const float* __restrict__ Wt, const float* __restrict__ bt,
    const float* __restrict__ Ws, const float* __restrict__ bs,
    const float* __restrict__ Wf, float* __restrict__ ws) {
  __shared__ float AL[64 * 65];
  __shared__ float BL[64 * 65];
  __shared__ float ML[64 * 65];
  const int t = threadIdx.x;
  uint* wsu = (uint*)ws;
  if (blockIdx.x < 8) {
    const int n = blockIdx.x;
#pragma unroll
    for (int i = 0; i < 16; ++i) {
      int idx = i * 256 + t;
      AL[(idx >> 6) * 65 + (idx & 63)] = Wt[n * 4096 + idx];
      BL[(idx >> 6) * 65 + (idx & 63)] = Ws[n * 4096 + idx];
    }
    __syncthreads();
#pragma unroll
    for (int i = 0; i < 16; ++i) {            // M[dp][d] = Wt[dp]·Ws[d] * TEMP
      int idx = i * 256 + t;
      int dp = idx >> 6, d = idx & 63;
      float acc = 0.f;
#pragma unroll 8
      for (int a = 0; a < 64; ++a) acc += AL[dp * 65 + a] * BL[d * 65 + a];
      ML[dp * 65 + d] = acc * TEMP;
    }
    if (t < 64) {
      float acc = 0.f;
#pragma unroll 8
      for (int a = 0; a < 64; ++a) acc += BL[t * 65 + a] * bt[n * 64 + a];
      ws[K_OFF + n * 64 + t] = acc * TEMP;
    } else if (t < 128) {
      int r = t - 64;
      float acc = 0.f;
#pragma unroll 8
      for (int a = 0; a < 64; ++a) acc += AL[r * 65 + a] * bs[n * 64 + a];
      ws[P_OFF + n * 64 + r] = acc * TEMP;
    } else if (t == 128) {
      float acc = 0.f;
      for (int a = 0; a < 64; ++a) acc += bt[n * 64 + a] * bs[n * 64 + a];
      ws[Q_OFF + n] = acc * TEMP;
    }
    __syncthreads();
#pragma unroll
    for (int i = 0; i < 16; ++i) {            // 4096 frag dwords (2-way split)
      int f = i * 256 + t;
      int r = f & 3, lane = (f >> 2) & 63, g = f >> 8;
      int s = g & 1, dt = (g >> 1) & 3, ks = g >> 3;
      int k = ks * 32 + ((lane >> 4) & 3) * 8 + r * 2;
      int d = dt * 16 + (lane & 15);
      uint lo = split_lvl2(ML[k * 65 + d], s);
      uint hi = split_lvl2(ML[(k + 1) * 65 + d], s);
      wsu[MFRAG + n * 4096 + (((ks * 4 + dt) * 2 + s) * 64 + lane) * 4 + r] =
          lo | (hi << 16);
    }
  } else if (blockIdx.x < 16) {
    const int n = blockIdx.x - 8;
#pragma unroll
    for (int i = 0; i < 16; ++i) {            // Wf rows n*64.. (k=dd, col=d)
      int idx = i * 256 + t;
      AL[(idx >> 6) * 65 + (idx & 63)] = Wf[(n * 64 + (idx >> 6)) * 64 + (idx & 63)];
    }
    __syncthreads();
#pragma unroll
    for (int i = 0; i < 16; ++i) {
      int f = i * 256 + t;
      int r = f & 3, lane = (f >> 2) & 63, g = f >> 8;
      int s = g & 1, dt = (g >> 1) & 3, ks = g >> 3;
      int k = ks * 32 + ((lane >> 4) & 3) * 8 + r * 2;
      int d = dt * 16 + (lane & 15);
      uint lo = split_lvl2(AL[k * 65 + d], s);
      uint hi = split_lvl2(AL[(k + 1) * 65 + d], s);
      wsu[WFRAG + n * 4096 + (((ks * 4 + dt) * 2 + s) * 64 + lane) * 4 + r] =
          lo | (hi << 16);
    }
  } else {
#pragma unroll
    for (int i = 0; i < 2; ++i) {
      int idx = i * 256 + t;                  // 0..511
      int n = idx >> 6, dp = idx & 63;
      float acc = 0.f;
#pragma unroll 8
      for (int a = 0; a < 64; ++a)
        acc += Wt[n * 4096 + dp * 64 + a] * bs[n * 64 + a];
      AL[idx] = acc * TEMP;                   // pL[n][dp]
    }
    __syncthreads();
#pragma unroll
    for (int i = 0; i < 4; ++i) {
      int f = i * 256 + t;
      int r = f & 3, lane = (f >> 2) & 63, g = f >> 8;
      int s = g & 1, ks = g >> 1;
      int k = ks * 32 + ((lane >> 4) & 3) * 8 + r * 2;
      int col = lane & 15;
      uint lo = (col < 8) ? (uint)split_lvl2(AL[col * 64 + k], s) : 0u;
      uint hi = (col < 8) ? (uint)split_lvl2(AL[col * 64 + k + 1], s) : 0u;
      wsu[PFRAG + ((ks * 2 + s) * 64 + lane) * 4 + r] = lo | (hi << 16);
    }
  }
}

// 2-way split-product cluster for global frags (verified R7)
#define SPLIT2_MFMA(FB, DT, CC)                                      \
  {                                                                  \
    short8 b00 = *(const short8*)&(FB)[((0 * 4 + (DT)) * 2 + 0) * 256]; \
    short8 b01 = *(const short8*)&(FB)[((0 * 4 + (DT)) * 2 + 1) * 256]; \
    short8 b10 = *(const short8*)&(FB)[((1 * 4 + (DT)) * 2 + 0) * 256]; \
    short8 b11 = *(const short8*)&(FB)[((1 * 4 + (DT)) * 2 + 1) * 256]; \
    CC = MFMA_B16(a00, b00, CC, 0, 0, 0);                            \
    CC = MFMA_B16(a10, b10, CC, 0, 0, 0);                            \
    CC = MFMA_B16(a00, b01, CC, 0, 0, 0);                            \
    CC = MFMA_B16(a01, b00, CC, 0, 0, 0);                            \
    CC = MFMA_B16(a10, b11, CC, 0, 0, 0);                            \
    CC = MFMA_B16(a11, b10, CC, 0, 0, 0);                            \
  }

// A-frag loads: a00/a10 = plane0 (k-chunk 0/1), a01/a11 = plane1
#define LOAD_A(BASEU, ROWSTR, PLANESTR, ROW, KOFF)                   \
  short8 a00 = *(const short8*)&(BASEU)[(ROW) * (ROWSTR) + (KOFF)];               \
  short8 a01 = *(const short8*)&(BASEU)[(PLANESTR) + (ROW) * (ROWSTR) + (KOFF)];  \
  short8 a10 = *(const short8*)&(BASEU)[(ROW) * (ROWSTR) + 32 + (KOFF)];          \
  short8 a11 = *(const short8*)&(BASEU)[(PLANESTR) + (ROW) * (ROWSTR) + 32 + (KOFF)];

// hs reg-staging index math (quad f = I*512 + t)
#define HV_LOAD(I, DST)                                                      \
  {                                                                          \
    const int f_ = (I) * 512 + t;                                            \
    const int p_ = f_ / 320;                                                 \
    const int s_ = f_ - p_ * 320;                                            \
    DST = *(const float4*)(hs_g + (size_t)(pair0 + p_) * 1280 +              \
                           (s_ >> 4) * 64 + (s_ & 15) * 4);                  \
  }
#define HV_STORE(I, SRC)                                                     \
  {                                                                          \
    const int f_ = (I) * 512 + t;                                            \
    const int p_ = f_ / 320;                                                 \
    const int s_ = f_ - p_ * 320;                                            \
    uint2 u0_, u1_; pksplit4(SRC, u0_, u1_);                                 \
    ushort* d_ = ldsu + HS2_U + p_ * 1440 + (s_ >> 4) * 72 + (s_ & 15) * 4;  \
    *(uint2*)d_ = u0_;                                                       \
    *(uint2*)(d_ + HS2_PL) = u1_;                                            \
  }

// ============================================================
// main: 8 pairs/block, 512 threads (8 waves), grid 4096, 2 blocks/CU.
// hs and V LDS-resident as producer-pre-split 2-plane bf16.
// ============================================================
__global__ __launch_bounds__(512, 4) void attn_kernel(
    const float* __restrict__ ht_g, const float* __restrict__ hs_g,
    const int* __restrict__ len_g, const float* __restrict__ bf,
    const float* __restrict__ wsp, float* __restrict__ out) {
  __shared__ __align__(16) float lds[LDS_FL];
  ushort* ldsu = (ushort*)lds;
  const int t    = threadIdx.x;
  const int lane = t & 63;
  const int w    = t >> 6;
  const int pair0 = blockIdx.x * 8;
  const uint* wsu = (const uint*)wsp;

  // ---------- stage ht (2-way bf16 split) + len ----------
  {
    float x = ht_g[(size_t)pair0 * 64 + t];
    ushort h0, h1; split2(x, h0, h1);
    const int p = t >> 6, dp = t & 63;
    ldsu[HT2_U + 0 * 640 + p * 80 + dp] = h0;
    ldsu[HT2_U + 1 * 640 + p * 80 + dp] = h1;
  }
  if (t < 8) lds[LEN_F + t] = (float)len_g[pair0 + t];
  __syncthreads();   // barrier A: ht2 visible

  const int lo4 = lane & 15, kg = lane >> 4;
  const int rp8 = lo4 & 7;

  // ---------- V phase (MFMA): wave = head n; V -> 2-plane bf16 -----------
  {
    const int n = w;
    LOAD_A(ldsu + HT2_U, 80, 640, rp8, kg * 8)
    const uint* fb = wsu + MFRAG + n * 4096 + lane * 4;
    const float* kb = &wsp[K_OFF + n * 64 + lo4];
    float kv0 = kb[0], kv1 = kb[16], kv2 = kb[32], kv3 = kb[48];
    f32x4 c0 = {kv0, kv0, kv0, kv0};
    f32x4 c1 = {kv1, kv1, kv1, kv1};
    f32x4 c2 = {kv2, kv2, kv2, kv2};
    f32x4 c3 = {kv3, kv3, kv3, kv3};
    SPLIT2_MFMA(fb, 0, c0)
    SPLIT2_MFMA(fb, 1, c1)
    SPLIT2_MFMA(fb, 2, c2)
    SPLIT2_MFMA(fb, 3, c3)
    if (kg < 2) {
#pragma unroll
      for (int reg = 0; reg < 4; ++reg) {
        const int p = kg * 4 + reg;
        ushort* vp = ldsu + V2_U + p * 584 + n * 72 + lo4;
        ushort h0, h1;
        split2(c0[reg], h0, h1); vp[0]  = h0; vp[V2_PL]      = h1;
        split2(c1[reg], h0, h1); vp[16] = h0; vp[V2_PL + 16] = h1;
        split2(c2[reg], h0, h1); vp[32] = h0; vp[V2_PL + 32] = h1;
        split2(c3[reg], h0, h1); vp[48] = h0; vp[V2_PL + 48] = h1;
      }
    }
  }

  // ---------- issue hs global loads (latency hides under c phase) --------
  float4 hv0, hv1, hv2, hv3, hv4;
  HV_LOAD(0, hv0) HV_LOAD(1, hv1) HV_LOAD(2, hv2) HV_LOAD(3, hv3) HV_LOAD(4, hv4)

  // ---------- c (MFMA, wave 0): c[p][n] = q[n] + ht_p·p_n ----------
  if (w == 0) {
    LOAD_A(ldsu + HT2_U, 80, 640, rp8, kg * 8)
    const uint* fbp = wsu + PFRAG + lane * 4;
    short8 b00 = *(const short8*)&fbp[0 * 256];
    short8 b01 = *(const short8*)&fbp[1 * 256];
    short8 b10 = *(const short8*)&fbp[2 * 256];
    short8 b11 = *(const short8*)&fbp[3 * 256];
    float qv = (lo4 < 8) ? wsp[Q_OFF + lo4] : 0.f;
    f32x4 cc = {qv, qv, qv, qv};
    cc = MFMA_B16(a00, b00, cc, 0, 0, 0);
    cc = MFMA_B16(a10, b10, cc, 0, 0, 0);
    cc = MFMA_B16(a00, b01, cc, 0, 0, 0);
    cc = MFMA_B16(a01, b00, cc, 0, 0, 0);
    cc = MFMA_B16(a10, b11, cc, 0, 0, 0);
    cc = MFMA_B16(a11, b10, cc, 0, 0, 0);
    if (kg < 2 && lo4 < 8) {
#pragma unroll
      for (int reg = 0; reg < 4; ++reg)
        lds[C_F + (kg * 4 + reg) * 8 + lo4] = cc[reg];
    }
  }

  // ---------- convert staged hs -> 2-plane bf16 LDS ----------
  HV_STORE(0, hv0) HV_STORE(1, hv1) HV_STORE(2, hv2) HV_STORE(3, hv3) HV_STORE(4, hv4)
  __syncthreads();   // barrier 1: V2, c, hs2 visible

  // ---------- P2 (MFMA): scores + softmax. wave = pair ----------
  // scores[m][n] = c[p][n] + sum_d hs2[m][d] * V2[n][d]  (2-plane x 2-plane)
  {
    const int p = w;
    const int n8 = rp8;
    const int lenp = (int)lds[LEN_F + p];
    const ushort* vb = ldsu + V2_U + p * 584 + n8 * 72;
    const short8 B00 = *(const short8*)&vb[kg * 8];                // ks0 s0
    const short8 B01 = *(const short8*)&vb[V2_PL + kg * 8];        // ks0 s1
    const short8 B10 = *(const short8*)&vb[32 + kg * 8];           // ks1 s0
    const short8 B11 = *(const short8*)&vb[V2_PL + 32 + kg * 8];   // ks1 s1
    const float cv = lds[C_F + p * 8 + n8];
    f32x4 acc0 = {cv, cv, cv, cv};
    f32x4 acc1 = {cv, cv, cv, cv};
    {
      const ushort* ab = ldsu + HS2_U + p * 1440;
      LOAD_A(ab, 72, HS2_PL, lo4, kg * 8)                          // rows 0..15
      acc0 = MFMA_B16(a00, B00, acc0, 0, 0, 0);
      acc0 = MFMA_B16(a10, B10, acc0, 0, 0, 0);
      acc0 = MFMA_B16(a00, B01, acc0, 0, 0, 0);
      acc0 = MFMA_B16(a01, B00, acc0, 0, 0, 0);
      acc0 = MFMA_B16(a10, B11, acc0, 0, 0, 0);
      acc0 = MFMA_B16(a11, B10, acc0, 0, 0, 0);
    }
    {
      const int row = (16 + lo4 < 20) ? (16 + lo4) : 19;           // clamp pad
      const ushort* ab = ldsu + HS2_U + p * 1440;
      LOAD_A(ab, 72, HS2_PL, row, kg * 8)
      acc1 = MFMA_B16(a00, B00, acc1, 0, 0, 0);
      acc1 = MFMA_B16(a10, B10, acc1, 0, 0, 0);
      acc1 = MFMA_B16(a00, B01, acc1, 0, 0, 0);
      acc1 = MFMA_B16(a01, B00, acc1, 0, 0, 0);
      acc1 = MFMA_B16(a10, B11, acc1, 0, 0, 0);
      acc1 = MFMA_B16(a11, B10, acc1, 0, 0, 0);
    }
    // softmax over m (R9-verified pattern)
    float e0[4], e1[4];
    float mx = NEGV;
#pragma unroll
    for (int r = 0; r < 4; ++r) {
      const int m0 = kg * 4 + r;
      const int m1 = 16 + kg * 4 + r;
      e0[r] = (m0 < lenp) ? acc0[r] : NEGV;
      e1[r] = (m1 < lenp) ? acc1[r] : NEGV;
      mx = fmaxf(mx, fmaxf(e0[r], e1[r]));
    }
    mx = fmaxf(mx, __shfl_xor(mx, 16));
    mx = fmaxf(mx, __shfl_xor(mx, 32));
    float sm = 0.f;
#pragma unroll
    for (int r = 0; r < 4; ++r) {
      e0[r] = __expf(e0[r] - mx);
      e1[r] = (kg == 0) ? __expf(e1[r] - mx) : 0.f;    // pad rows m>=20 -> 0
      sm += e0[r] + e1[r];
    }
    sm += __shfl_xor(sm, 16);
    sm += __shfl_xor(sm, 32);
    const float inv = 1.0f / sm;
    if (lo4 < 8) {
#pragma unroll
      for (int r = 0; r < 4; ++r)
        lds[ATT_F + p * 240 + (kg * 4 + r) * 12 + lo4] = e0[r] * inv;
      if (kg == 0) {
#pragma unroll
        for (int r = 0; r < 4; ++r)
          lds[ATT_F + p * 240 + (16 + r) * 12 + lo4] = e1[r] * inv;
      }
    }
  }
  // no barrier: P3 pair-local (same wave wrote this pair's attn)

  // ---------- P3: wv (hs plane-0) + 2-plane split into V2 overlay --------
  {
    const int p = w, d = lane;
    const ushort* hsb = ldsu + HS2_U + p * 1440;
    float wv[8] = {0.f, 0.f, 0.f, 0.f, 0.f, 0.f, 0.f, 0.f};
    const float* atp = &lds[ATT_F + p * 240];
#pragma unroll
    for (int m_ = 0; m_ < 20; ++m_) {
      const float h = bf16_f(hsb[m_ * 72 + d]);
      const float4 a0 = *(const float4*)&atp[m_ * 12];
      const float4 a1 = *(const float4*)&atp[m_ * 12 + 4];
      wv[0] += a0.x * h; wv[1] += a0.y * h; wv[2] += a0.z * h; wv[3] += a0.w * h;
      wv[4] += a1.x * h; wv[5] += a1.y * h; wv[6] += a1.z * h; wv[7] += a1.w * h;
    }
    ushort* wp = ldsu + V2_U + p * 584;        // overlay V2 (dead after P2)
#pragma unroll
    for (int n = 0; n < 8; ++n) {
      ushort h0, h1; split2(wv[n], h0, h1);
      wp[n * 72 + d] = h0;
      wp[V2_PL + n * 72 + d] = h1;
    }
  }
  __syncthreads();   // barrier 2: all wv visible; hs2 arena dead

  // ---------- P4a (MFMA): wave (dt = w&3, ng = w>>2) ----------
  {
    const int dt = w & 3, ng = w >> 2;
    f32x4 cc = {0.f, 0.f, 0.f, 0.f};
#pragma unroll
    for (int nn = 0; nn < 4; ++nn) {
      const int n = ng * 4 + nn;
      LOAD_A(ldsu + V2_U, 584, V2_PL, rp8, n * 72 + kg * 8)
      const uint* fb = wsu + WFRAG + n * 4096 + lane * 4;
      SPLIT2_MFMA(fb, dt, cc)
    }
    if (kg < 2) {
#pragma unroll
      for (int reg = 0; reg < 4; ++reg)
        lds[0 + ng * 512 + (kg * 4 + reg) * 64 + dt * 16 + lo4] = cc[reg];
    }
  }
  __syncthreads();   // barrier 3

  // ---------- P4b: out = bf + y0 + y1 ----------
  {
    const int d = t & 63;
    out[(size_t)pair0 * 64 + t] = bf[d] + lds[t] + lds[512 + t];
  }
}

extern "C" void kernel_launch(void* const* d_in, const int* in_sizes, int n_in,
                              void* d_out, int out_size, void* d_ws, size_t ws_size,
                              hipStream_t stream) {
  const float* ht  = (const float*)d_in[0];
  const float* hs  = (const float*)d_in[1];
  const int*   len = (const int*)d_in[2];
  const float* Wt  = (const float*)d_in[3];
  const float* bt  = (const float*)d_in[4];
  const float* Ws  = (const float*)d_in[5];
  const float* bs  = (const float*)d_in[6];
  const float* Wf  = (const float*)d_in[7];
  const float* bf  = (const float*)d_in[8];
  float* outp = (float*)d_out;
  float* ws   = (float*)d_ws;

  hipLaunchKernelGGL(prep_kernel, dim3(17), dim3(256), 0, stream,
                     Wt, bt, Ws, bs, Wf, ws);
  hipLaunchKernelGGL(attn_kernel, dim3(4096), dim3(512), 0, stream,
                     ht, hs, len, bf, ws, outp);
}